// Round 1
// baseline (4088.290 us; speedup 1.0000x reference)
//
#include <hip/hip_runtime.h>

typedef unsigned int  u32;
typedef unsigned short u16;
typedef float v2f __attribute__((ext_vector_type(2)));

// B=8, NS=80, NN=81, H=256, L=2, STEPS=8, VOCAB=30000
#define ROWS 648          // B*NN

__device__ __forceinline__ float sigf(float x){ return 1.0f/(1.0f+__expf(-x)); }
__device__ __forceinline__ float tanh_fast(float x){
  float e = __expf(-2.0f*fabsf(x));
  float r = (1.0f-e)/(1.0f+e);
  return copysignf(r,x);
}
__device__ __forceinline__ u16 f2bf(float f){        // RTNE f32->bf16
  u32 u = __float_as_uint(f);
  u += 0x7FFFu + ((u>>16)&1u);
  return (u16)(u>>16);
}
__device__ __forceinline__ u32 packbf2(float lo, float hi){
  return (u32)f2bf(lo) | ((u32)f2bf(hi)<<16);
}
__device__ __forceinline__ float bf2f(u16 v){ return __uint_as_float(((u32)v)<<16); }
__device__ __forceinline__ float bflo(u32 u){ return __uint_as_float(u<<16); }
__device__ __forceinline__ float bfhi(u32 u){ return __uint_as_float(u & 0xFFFF0000u); }
__device__ __forceinline__ v2f unpk(u32 w){
  v2f r; r.x = bflo(w); r.y = bfhi(w); return r;
}
// dual-issue packed fp32 FMA: c = a*b + c (compiler does not auto-select v_pk_fma_f32)
__device__ __forceinline__ v2f pk_fma(v2f a, v2f b, v2f c){
  asm("v_pk_fma_f32 %0, %1, %2, %0" : "+v"(c) : "v"(a), "v"(b));
  return c;
}

// ---------------- weight packing ----------------------------------------
// gate-quad, k-pair layout: dst[k2*1024 + j*4 + g] = pack(src[2k2][g*256+j], src[2k2+1][g*256+j])
__global__ void pack_gates(const float* __restrict__ A, const float* __restrict__ Bm,
                           u32* __restrict__ dst, int Krows){
  int id = blockIdx.x*256 + threadIdx.x;
  int tot = (Krows>>1)*1024;
  if (id >= tot) return;
  int k2 = id >> 10;
  int c  = id & 1023;
  int j = c >> 2, g = c & 3;
  int k0 = 2*k2, k1 = 2*k2+1;
  float v0 = (k0<256) ? A[k0*1024 + g*256 + j] : Bm[(k0-256)*1024 + g*256 + j];
  float v1 = (k1<256) ? A[k1*1024 + g*256 + j] : Bm[(k1-256)*1024 + g*256 + j];
  dst[id] = packbf2(v0, v1);
}

__global__ void pack_pairs(const float* __restrict__ src, u32* __restrict__ dst,
                           int Kpairs, int ncol){
  int id = blockIdx.x*256 + threadIdx.x;
  if (id >= Kpairs*ncol) return;
  int k2 = id / ncol, j = id - k2*ncol;
  dst[id] = packbf2(src[(2*k2)*ncol + j], src[(2*k2+1)*ncol + j]);
}

__global__ void k_init_p(float* __restrict__ p0){
  int i = blockIdx.x*256 + threadIdx.x;
  if (i < ROWS) p0[i] = ((i % 81)==0) ? 1.0f : 0.0f;
}

// ---------------- K1: statement embedder + X0 precompute ----------------
__global__ __launch_bounds__(512) void k_stmt_x0(
    const float* __restrict__ ne, const float* __restrict__ stWx, const float* __restrict__ stb,
    const float* __restrict__ skWx, const float* __restrict__ skb, float4* __restrict__ X0){
  __shared__ float xv[2][256];
  __shared__ float hv[2][256];
  int r = threadIdx.x >> 8, j = threadIdx.x & 255;
  int bn = blockIdx.x*2 + r;                    // 0..639
  xv[r][j] = ne[bn*256 + j];
  __syncthreads();
  float a0=stb[j], a2=stb[512+j], a3=stb[768+j];
  for (int k=0;k<256;k++){
    float x = xv[r][k];
    const float* w = stWx + k*1024;
    a0 = fmaf(x, w[j], a0); a2 = fmaf(x, w[512+j], a2); a3 = fmaf(x, w[768+j], a3);
  }
  float c = sigf(a0)*tanh_fast(a2);
  float h = sigf(a3)*tanh_fast(c);
  hv[r][j] = h;
  __syncthreads();
  a0=stb[1024+j]; a2=stb[1536+j]; a3=stb[1792+j];
  const float* W1 = stWx + 256*1024;
  for (int k=0;k<256;k++){
    float x = hv[r][k];
    const float* w = W1 + k*1024;
    a0 = fmaf(x, w[j], a0); a2 = fmaf(x, w[512+j], a2); a3 = fmaf(x, w[768+j], a3);
  }
  c = sigf(a0)*tanh_fast(a2);
  h = sigf(a3)*tanh_fast(c);
  __syncthreads();
  xv[r][j] = h;           // stmt row
  __syncthreads();
  float b0=skb[j], b1g=skb[256+j], b2=skb[512+j], b3=skb[768+j];
  for (int k=0;k<256;k++){
    float x = xv[r][k];
    const float* w = skWx + k*1024;
    b0 = fmaf(x, w[j], b0);     b1g = fmaf(x, w[256+j], b1g);
    b2 = fmaf(x, w[512+j], b2); b3 = fmaf(x, w[768+j], b3);
  }
  X0[bn*256 + j] = make_float4(b0,b1g,b2,b3);
}

// ---------------- K3: skip-encoder chains (v3) ---------------------------
// grid = (s 0..79) x (batch-half); 1024 threads.
//   matvec role: tid = kh*256+j (kh = k-slice 0..3)  — each weight uint4
//     loaded ONCE per block, serves 4 batch rows (acc[4][4] v2f in regs).
//   cell role:   tid = rr*256+j (rr = batch row 0..3) — gate reduce over kh
//     partials in LDS, LSTM cell, LayerNorm.
// v3: v_pk_fma_f32 inline asm for all v2f accumulates (dual-issue fp32);
//     part[] padded so LDS > 80KB => hard 1 block/CU.
__global__ __launch_bounds__(1024) void k_skip_chains(
    const float4* __restrict__ X0,
    const uint4* __restrict__ W0, const uint4* __restrict__ W1,
    const float* __restrict__ skb, const float* __restrict__ lnS, const float* __restrict__ lnB,
    float* __restrict__ skip){
  int s  = blockIdx.x >> 1;
  int bh = blockIdx.x & 1;
  int tid = threadIdx.x;
  int kh = tid >> 8, j = tid & 255;     // matvec role
  int rr = kh;                          // cell role row
  int b  = bh*4 + rr;
  __shared__ float part[17664];         // 69KB ([kh][row][gate][j] uses 16384; rest pads LDS >80KB)
  __shared__ float h0buf[128*8];        // [k2][row][2] layer0 input (LN'd h0)
  __shared__ float in1buf[256*8];       // [k2][row][2] layer1 input [h0_raw | h1_ln]
  __shared__ float red[4][8];
  for (int i=tid; i<128*8; i+=1024) h0buf[i]=0.f;
  for (int i=tid; i<256*8; i+=1024) in1buf[i]=0.f;
  float c0=0.f, c1=0.f;                 // state of (row rr, col j)
  float s1b0=skb[1024+j], s1b1=skb[1280+j], s1b2=skb[1536+j], s1b3=skb[1792+j];
  float lS0=lnS[j], lS1=lnS[256+j], lS2=lnS[512+j], lS3=lnS[768+j];
  float lB0=lnB[j], lB1=lnB[256+j], lB2=lnB[512+j], lB3=lnB[768+j];
  __syncthreads();
  for (int idx=s; idx<80; idx++){
    float4 gx = X0[(b*80+idx)*256 + j];     // issue early; used in cell phase
    // ---- layer0 matvec: h0 @ Wh0, k2 slice [kh*32, kh*32+32)
    v2f acc[4][4];
    #pragma unroll
    for (int r4=0;r4<4;r4++){
      #pragma unroll
      for (int g=0;g<4;g++) acc[r4][g]=(v2f){0.f,0.f};
    }
    #pragma unroll 4
    for (int k2=kh*32; k2<kh*32+32; k2++){
      uint4 w = W0[k2*256+j];
      v2f w0=unpk(w.x), w1=unpk(w.y), w2=unpk(w.z), w3=unpk(w.w);
      const float* hb = &h0buf[k2*8];
      #pragma unroll
      for (int r4=0;r4<4;r4++){
        v2f hp = *(const v2f*)&hb[r4*2];
        acc[r4][0] = pk_fma(hp, w0, acc[r4][0]);
        acc[r4][1] = pk_fma(hp, w1, acc[r4][1]);
        acc[r4][2] = pk_fma(hp, w2, acc[r4][2]);
        acc[r4][3] = pk_fma(hp, w3, acc[r4][3]);
      }
    }
    #pragma unroll
    for (int r4=0;r4<4;r4++){
      #pragma unroll
      for (int g=0;g<4;g++)
        part[((kh*4+r4)*4+g)*256 + j] = acc[r4][g].x + acc[r4][g].y;
    }
    __syncthreads();
    // ---- layer0 cell (rr, j)
    float a0=gx.x, a1=gx.y, a2=gx.z, a3=gx.w;   // X0 includes sk_b0
    #pragma unroll
    for (int k=0;k<4;k++){
      a0 += part[((k*4+rr)*4+0)*256+j];
      a1 += part[((k*4+rr)*4+1)*256+j];
      a2 += part[((k*4+rr)*4+2)*256+j];
      a3 += part[((k*4+rr)*4+3)*256+j];
    }
    float ii=sigf(a0), ff=sigf(a1), gg=tanh_fast(a2), oo=sigf(a3);
    c0 = ff*c0 + ii*gg;
    float h0n = oo*tanh_fast(c0);
    in1buf[(j>>1)*8 + rr*2 + (j&1)] = h0n;      // raw h0 -> layer1 input half
    __syncthreads();
    // ---- layer1 matvec: [h0_raw|h1_ln] @ [Wx1;Wh1], k2 slice [kh*64, kh*64+64)
    #pragma unroll
    for (int r4=0;r4<4;r4++){
      #pragma unroll
      for (int g=0;g<4;g++) acc[r4][g]=(v2f){0.f,0.f};
    }
    #pragma unroll 4
    for (int k2=kh*64; k2<kh*64+64; k2++){
      uint4 w = W1[k2*256+j];
      v2f w0=unpk(w.x), w1=unpk(w.y), w2=unpk(w.z), w3=unpk(w.w);
      const float* hb = &in1buf[k2*8];
      #pragma unroll
      for (int r4=0;r4<4;r4++){
        v2f hp = *(const v2f*)&hb[r4*2];
        acc[r4][0] = pk_fma(hp, w0, acc[r4][0]);
        acc[r4][1] = pk_fma(hp, w1, acc[r4][1]);
        acc[r4][2] = pk_fma(hp, w2, acc[r4][2]);
        acc[r4][3] = pk_fma(hp, w3, acc[r4][3]);
      }
    }
    #pragma unroll
    for (int r4=0;r4<4;r4++){
      #pragma unroll
      for (int g=0;g<4;g++)
        part[((kh*4+r4)*4+g)*256 + j] = acc[r4][g].x + acc[r4][g].y;
    }
    __syncthreads();
    // ---- layer1 cell (rr, j)
    a0=s1b0; a1=s1b1; a2=s1b2; a3=s1b3;
    #pragma unroll
    for (int k=0;k<4;k++){
      a0 += part[((k*4+rr)*4+0)*256+j];
      a1 += part[((k*4+rr)*4+1)*256+j];
      a2 += part[((k*4+rr)*4+2)*256+j];
      a3 += part[((k*4+rr)*4+3)*256+j];
    }
    ii=sigf(a0); ff=sigf(a1); gg=tanh_fast(a2); oo=sigf(a3);
    c1 = ff*c1 + ii*gg;
    float h1n = oo*tanh_fast(c1);
    skip[((b*81 + s)*81 + (idx+1))*256 + j] = h1n;   // pre-LN output
    // ---- LayerNorm over concat(c0,h0n,c1,h1n) per row (1024 elems)
    float sm = c0 + h0n + c1 + h1n;
    float sq = c0*c0 + h0n*h0n + c1*c1 + h1n*h1n;
    #pragma unroll
    for (int off=32; off; off>>=1){ sm += __shfl_xor(sm, off); sq += __shfl_xor(sq, off); }
    int wq = j >> 6;
    if ((j & 63) == 0){ red[rr][wq] = sm; red[rr][4+wq] = sq; }
    __syncthreads();
    sm = red[rr][0]+red[rr][1]+red[rr][2]+red[rr][3];
    sq = red[rr][4]+red[rr][5]+red[rr][6]+red[rr][7];
    float mu = sm * (1.0f/1024.0f);
    float var = sq * (1.0f/1024.0f) - mu*mu;
    float rstd = rsqrtf(var + 1e-6f);
    c0 = (c0 - mu)*rstd*lS0 + lB0;
    float h0ln = (h0n - mu)*rstd*lS1 + lB1;
    c1 = (c1 - mu)*rstd*lS2 + lB2;
    float h1ln = (h1n - mu)*rstd*lS3 + lB3;
    h0buf[(j>>1)*8 + rr*2 + (j&1)] = h0ln;
    in1buf[(128+(j>>1))*8 + rr*2 + (j&1)] = h1ln;
    __syncthreads();
  }
}

// ---------------- K4: keys = skip @ ws + bs  (bf16 out) ------------------
__global__ __launch_bounds__(256) void k_keys(const float* __restrict__ skip,
    const u32* __restrict__ wspk, const float* __restrict__ bs, u16* __restrict__ keys){
  __shared__ float skr[8][256];
  int tid = threadIdx.x;
  int bn = blockIdx.x;
  float bsv = bs[tid];
  const float4* sk4 = (const float4*)skip;
  for (int m0=0; m0<81; m0+=8){
    int mc = (81-m0 < 8) ? (81-m0) : 8;
    for (int i=tid; i<mc*64; i+=256){
      int mm = i>>6, kk = i&63;
      float4 v = sk4[(bn*81 + m0 + mm)*64 + kk];
      skr[mm][4*kk+0]=v.x; skr[mm][4*kk+1]=v.y; skr[mm][4*kk+2]=v.z; skr[mm][4*kk+3]=v.w;
    }
    __syncthreads();
    v2f acc[8];
    #pragma unroll
    for (int qq=0;qq<8;qq++) acc[qq]=(v2f){0.f,0.f};
    for (int k2=0;k2<128;k2++){
      v2f w2 = unpk(wspk[k2*256+tid]);
      #pragma unroll
      for (int qq=0;qq<8;qq++){
        v2f sv = *(const v2f*)&skr[qq][2*k2];
        acc[qq] = pk_fma(sv, w2, acc[qq]);
      }
    }
    for (int qq=0;qq<mc;qq++) keys[(bn*81+m0+qq)*256+tid] = f2bf(acc[qq].x+acc[qq].y+bsv);
    __syncthreads();
  }
}

// ---------------- Kb: fused q + logits -> softmax -> t -------------------
// mode 0: only m==1; mode 1: m>n || m==80; mode 2: only m==80
__global__ __launch_bounds__(256) void k_attn(
    const float* __restrict__ c0g, const float* __restrict__ h0g,
    const float* __restrict__ c1g, const float* __restrict__ h1g,
    const u32* __restrict__ wkp, const float* __restrict__ bk,
    const u16* __restrict__ keys, const float* __restrict__ w1,
    const float* __restrict__ pcur, float* __restrict__ t, int mode){
  int bn = blockIdx.x; int n = bn % 81;
  int tid = threadIdx.x;
  float pv = pcur[bn];
  if (pv == 0.0f){
    if (tid < 81) t[bn*81 + tid] = 0.0f;
    return;
  }
  __shared__ float hc[1024];
  __shared__ float qv[256];
  __shared__ float lg[81];
  hc[tid]      = c0g[bn*256+tid];
  hc[256+tid]  = h0g[bn*256+tid];
  hc[512+tid]  = c1g[bn*256+tid];
  hc[768+tid]  = h1g[bn*256+tid];
  if (tid < 81) lg[tid] = -3e38f;
  __syncthreads();
  v2f A = {bk[tid], 0.f};
  #pragma unroll 8
  for (int k2=0;k2<512;k2++){
    v2f hp = *(const v2f*)&hc[2*k2];
    A = pk_fma(hp, unpk(wkp[k2*256+tid]), A);
  }
  qv[tid] = A.x + A.y;
  __syncthreads();
  int lane = tid & 63, wv = tid >> 6;
  float w1v0 = w1[lane], w1v1 = w1[64+lane], w1v2 = w1[128+lane], w1v3 = w1[192+lane];
  for (int m = wv; m < 81; m += 4){
    bool um = (mode==0) ? (m==1) : (mode==2) ? (m==80) : (m>n || m==80);
    if (!um) continue;
    const u16* kr = keys + (bn*81+m)*256;
    float acc;
    acc  = tanh_fast(qv[lane]     + bf2f(kr[lane]))     * w1v0;
    acc += tanh_fast(qv[64+lane]  + bf2f(kr[64+lane]))  * w1v1;
    acc += tanh_fast(qv[128+lane] + bf2f(kr[128+lane])) * w1v2;
    acc += tanh_fast(qv[192+lane] + bf2f(kr[192+lane])) * w1v3;
    #pragma unroll
    for (int off=32; off; off>>=1) acc += __shfl_xor(acc, off);
    if (lane==0) lg[m] = acc;      // b1 omitted: softmax-invariant
  }
  __syncthreads();
  if (tid < 64){
    float v1 = lg[tid];
    float v2 = (tid<17) ? lg[64+tid] : -3e38f;
    float mx = fmaxf(v1, v2);
    #pragma unroll
    for (int off=32; off; off>>=1) mx = fmaxf(mx, __shfl_xor(mx, off));
    float e1 = __expf(v1-mx);
    float e2 = (tid<17) ? __expf(v2-mx) : 0.0f;
    float ssum = e1+e2;
    #pragma unroll
    for (int off=32; off; off>>=1) ssum += __shfl_xor(ssum, off);
    float sc = pv / ssum;
    t[bn*81 + tid] = e1*sc;
    if (tid<17) t[bn*81 + 64+tid] = e2*sc;
  }
}

// ---------------- Kc: x_in/prop einsums + ex-LSTM step + new_p -----------
__global__ __launch_bounds__(1024) void k_update(
    const float* __restrict__ t, const float* __restrict__ skip,
    const float* __restrict__ c0i, const float* __restrict__ h0i,
    const float* __restrict__ c1i, const float* __restrict__ h1i,
    const uint4* __restrict__ WA, const uint4* __restrict__ WB,
    const float* __restrict__ exb,
    float* __restrict__ c0o, float* __restrict__ h0o,
    float* __restrict__ c1o, float* __restrict__ h1o,
    float* __restrict__ pnext){
  int rr = threadIdx.x >> 8, j = threadIdx.x & 255;
  int row = blockIdx.x*4 + rr;
  int b = row / 81, m = row - b*81;
  __shared__ float tcol[4][81];
  __shared__ float xh[4][5120];   // row stride padded: LDS total >80KB => 1 block/CU
  if (j < 81) tcol[rr][j] = t[(b*81 + j)*81 + m];
  __syncthreads();
  float xa=0.f, c0p=0.f, h0p=0.f, c1p=0.f, h1p=0.f, ts=0.f;
  for (int n=0;n<81;n++){
    float tv = tcol[rr][n];
    ts += tv;
    if (tv != 0.0f){
      xa  = fmaf(tv, skip[((b*81+n)*81 + m)*256 + j], xa);
      int st = (b*81+n)*256 + j;
      c0p = fmaf(tv, c0i[st], c0p);
      h0p = fmaf(tv, h0i[st], h0p);
      c1p = fmaf(tv, c1i[st], c1p);
      h1p = fmaf(tv, h1i[st], h1p);
    }
  }
  bool alive = (ts != 0.0f);
  float inv = 1.0f/(ts + 1e-7f);
  xa*=inv; c0p*=inv; h0p*=inv; c1p*=inv; h1p*=inv;
  if (j==0) pnext[row] = ts;
  xh[rr][j] = xa; xh[rr][256+j] = h0p;
  __syncthreads();
  float c0n=0.f, h0n=0.f;
  if (alive){
    v2f A0={exb[j],0.f}, A1={exb[256+j],0.f}, A2={exb[512+j],0.f}, A3={exb[768+j],0.f};
    #pragma unroll 8
    for (int k2=0;k2<256;k2++){
      v2f hp = *(const v2f*)&xh[rr][2*k2];
      uint4 w = WA[k2*256+j];
      A0 = pk_fma(hp, unpk(w.x), A0); A1 = pk_fma(hp, unpk(w.y), A1);
      A2 = pk_fma(hp, unpk(w.z), A2); A3 = pk_fma(hp, unpk(w.w), A3);
    }
    float a0=A0.x+A0.y, a1=A1.x+A1.y, a2=A2.x+A2.y, a3=A3.x+A3.y;
    c0n = sigf(a1)*c0p + sigf(a0)*tanh_fast(a2);
    h0n = sigf(a3)*tanh_fast(c0n);
  }
  __syncthreads();
  xh[rr][j] = h0n; xh[rr][256+j] = h1p;
  __syncthreads();
  if (alive){
    v2f A0={exb[1024+j],0.f}, A1={exb[1280+j],0.f}, A2={exb[1536+j],0.f}, A3={exb[1792+j],0.f};
    #pragma unroll 8
    for (int k2=0;k2<256;k2++){
      v2f hp = *(const v2f*)&xh[rr][2*k2];
      uint4 w = WB[k2*256+j];
      A0 = pk_fma(hp, unpk(w.x), A0); A1 = pk_fma(hp, unpk(w.y), A1);
      A2 = pk_fma(hp, unpk(w.z), A2); A3 = pk_fma(hp, unpk(w.w), A3);
    }
    float a0=A0.x+A0.y, a1=A1.x+A1.y, a2=A2.x+A2.y, a3=A3.x+A3.y;
    float c1n = sigf(a1)*c1p + sigf(a0)*tanh_fast(a2);
    float h1n = sigf(a3)*tanh_fast(c1n);
    int o = row*256 + j;
    c0o[o]=c0n; h0o[o]=h0n; c1o[o]=c1n; h1o[o]=h1n;
  }
}

// ---------------- K6: out = h_exit @ wo + bo -----------------------------
__global__ __launch_bounds__(256) void k_out(
    const float* __restrict__ h1f, const int* __restrict__ exitIdx,
    const float* __restrict__ wo, const float* __restrict__ bo, float* __restrict__ out){
  __shared__ float hv[8][256];
  int tid = threadIdx.x;
  for (int i = tid; i < 2048; i += 256){
    int b = i >> 8, k = i & 255;
    hv[b][k] = h1f[(b*81 + exitIdx[b])*256 + k];
  }
  __syncthreads();
  int v = blockIdx.x*256 + tid;
  if (v >= 30000) return;
  float acc[8];
  #pragma unroll
  for (int b=0;b<8;b++) acc[b] = bo[v];
  for (int k=0;k<256;k++){
    float w = wo[k*30000 + v];
    #pragma unroll
    for (int b=0;b<8;b++) acc[b] = fmaf(hv[b][k], w, acc[b]);
  }
  #pragma unroll
  for (int b=0;b<8;b++) out[b*30000+v] = acc[b];
}

// ---------------- launch --------------------------------------------------
extern "C" void kernel_launch(void* const* d_in, const int* in_sizes, int n_in,
                              void* d_out, int out_size, void* d_ws, size_t ws_size,
                              hipStream_t stream){
  (void)in_sizes; (void)n_in; (void)out_size;
  const float* ne    = (const float*)d_in[0];
  const int*   exitI = (const int*)d_in[10];
  const float* stWx  = (const float*)d_in[12];
  const float* stb   = (const float*)d_in[14];
  const float* skWx  = (const float*)d_in[15];
  const float* skWh  = (const float*)d_in[16];
  const float* skb   = (const float*)d_in[17];
  const float* lnS   = (const float*)d_in[18];
  const float* lnB   = (const float*)d_in[19];
  const float* exWx  = (const float*)d_in[20];
  const float* exWh  = (const float*)d_in[21];
  const float* exb   = (const float*)d_in[22];
  const float* wk    = (const float*)d_in[23];
  const float* bk    = (const float*)d_in[24];
  const float* wsm   = (const float*)d_in[25];
  const float* bs    = (const float*)d_in[26];
  const float* w1    = (const float*)d_in[27];
  const float* wo    = (const float*)d_in[29];
  const float* bo    = (const float*)d_in[30];
  float* out = (float*)d_out;

  char* w = (char*)d_ws;
  size_t off = 0;
  auto alloc = [&](size_t bytes)->char*{
    char* p = w + off; off += (bytes + 255) & ~size_t(255); return p;
  };
  float4* X0   = (float4*)alloc((size_t)640*256*16);
  u32* W0pk    = (u32*)alloc((size_t)128*1024*4);
  u32* W1pk    = (u32*)alloc((size_t)256*1024*4);
  u32* WApk    = (u32*)alloc((size_t)256*1024*4);
  u32* WBpk    = (u32*)alloc((size_t)256*1024*4);
  u32* wkp     = (u32*)alloc((size_t)512*256*4);
  u32* wspk    = (u32*)alloc((size_t)128*256*4);
  float* skip  = (float*)alloc((size_t)8*81*81*256*4);   // fp32
  u16* keys    = (u16*)alloc((size_t)8*81*81*256*2);     // bf16
  float* tb    = (float*)alloc((size_t)ROWS*81*4);
  float* p0    = (float*)alloc(ROWS*4);
  float* p1    = (float*)alloc(ROWS*4);
  float* stA   = (float*)alloc((size_t)4*ROWS*256*4);
  float* stB   = (float*)alloc((size_t)4*ROWS*256*4);
  if (off > ws_size) return;   // workspace too small — surfaces as absmax fail

  const size_t ST = (size_t)ROWS*256;
  float *A_c0=stA, *A_h0=stA+ST, *A_c1=stA+2*ST, *A_h1=stA+3*ST;
  float *B_c0=stB, *B_h0=stB+ST, *B_c1=stB+2*ST, *B_h1=stB+3*ST;

  hipMemsetAsync(skip, 0, (size_t)8*81*81*256*4, stream);
  hipMemsetAsync(stA, 0, (size_t)4*ROWS*256*4, stream);
  hipMemsetAsync(stB, 0, (size_t)4*ROWS*256*4, stream);
  k_init_p<<<3,256,0,stream>>>(p0);

  pack_gates<<<512, 256, 0, stream>>>(skWh, skWh, W0pk, 256);                       // Wh0
  pack_gates<<<1024,256, 0, stream>>>(skWx+256*1024, skWh+256*1024, W1pk, 512);     // [Wx1;Wh1]
  pack_gates<<<1024,256, 0, stream>>>(exWx, exWh, WApk, 512);                       // [exWx0;exWh0]
  pack_gates<<<1024,256, 0, stream>>>(exWx+256*1024, exWh+256*1024, WBpk, 512);     // [exWx1;exWh1]
  pack_pairs<<<512, 256, 0, stream>>>(wk, wkp, 512, 256);
  pack_pairs<<<128, 256, 0, stream>>>(wsm, wspk, 128, 256);

  k_stmt_x0<<<320, 512, 0, stream>>>(ne, stWx, stb, skWx, skb, X0);
  k_skip_chains<<<160, 1024, 0, stream>>>(X0, (const uint4*)W0pk, (const uint4*)W1pk,
                                          skb, lnS, lnB, skip);
  k_keys<<<648, 256, 0, stream>>>(skip, wspk, bs, keys);

  float* pc = p0; float* pn = p1;
  for (int s=0; s<8; s++){
    float *ic0,*ih0,*ic1,*ih1,*oc0,*oh0,*oc1,*oh1;
    if ((s & 1) == 0){ ic0=A_c0; ih0=A_h0; ic1=A_c1; ih1=A_h1; oc0=B_c0; oh0=B_h0; oc1=B_c1; oh1=B_h1; }
    else             { ic0=B_c0; ih0=B_h0; ic1=B_c1; ih1=B_h1; oc0=A_c0; oh0=A_h0; oc1=A_c1; oh1=A_h1; }
    int mode = (s==0) ? 0 : ((s==7) ? 2 : 1);
    k_attn<<<648, 256, 0, stream>>>(ic0, ih0, ic1, ih1, wkp, bk, keys, w1, pc, tb, mode);
    k_update<<<162, 1024, 0, stream>>>(tb, skip, ic0, ih0, ic1, ih1,
                                       (const uint4*)WApk, (const uint4*)WBpk, exb,
                                       oc0, oh0, oc1, oh1, pn);
    float* tmp = pc; pc = pn; pn = tmp;
  }
  // final states are in buffer A (step 7 writes A)
  k_out<<<(30000+255)/256, 256, 0, stream>>>(A_h1, exitI, wo, bo, out);
}

// Round 2
// 2739.300 us; speedup vs baseline: 1.4925x; 1.4925x over previous
//
#include <hip/hip_runtime.h>

typedef unsigned int  u32;
typedef unsigned short u16;
typedef float v2f __attribute__((ext_vector_type(2)));
typedef __attribute__((ext_vector_type(8))) short bfv8;   // 8 bf16 = 4 VGPR
typedef __attribute__((ext_vector_type(4))) float f32x4;

// B=8, NS=80, NN=81, H=256, L=2, STEPS=8, VOCAB=30000
#define ROWS 648          // B*NN

__device__ __forceinline__ float sigf(float x){ return 1.0f/(1.0f+__expf(-x)); }
__device__ __forceinline__ float tanh_fast(float x){
  float e = __expf(-2.0f*fabsf(x));
  float r = (1.0f-e)/(1.0f+e);
  return copysignf(r,x);
}
__device__ __forceinline__ u16 f2bf(float f){        // RTNE f32->bf16
  u32 u = __float_as_uint(f);
  u += 0x7FFFu + ((u>>16)&1u);
  return (u16)(u>>16);
}
__device__ __forceinline__ u32 packbf2(float lo, float hi){
  return (u32)f2bf(lo) | ((u32)f2bf(hi)<<16);
}
__device__ __forceinline__ float bf2f(u16 v){ return __uint_as_float(((u32)v)<<16); }
__device__ __forceinline__ float bflo(u32 u){ return __uint_as_float(u<<16); }
__device__ __forceinline__ float bfhi(u32 u){ return __uint_as_float(u & 0xFFFF0000u); }
__device__ __forceinline__ v2f unpk(u32 w){
  v2f r; r.x = bflo(w); r.y = bfhi(w); return r;
}

// ---------------- weight packing ----------------------------------------
// gate-quad, k-pair layout (k_update weights): dst[k2*1024 + j*4 + g]
__global__ void pack_gates(const float* __restrict__ A, const float* __restrict__ Bm,
                           u32* __restrict__ dst, int Krows){
  int id = blockIdx.x*256 + threadIdx.x;
  int tot = (Krows>>1)*1024;
  if (id >= tot) return;
  int k2 = id >> 10;
  int c  = id & 1023;
  int j = c >> 2, g = c & 3;
  int k0 = 2*k2, k1 = 2*k2+1;
  float v0 = (k0<256) ? A[k0*1024 + g*256 + j] : Bm[(k0-256)*1024 + g*256 + j];
  float v1 = (k1<256) ? A[k1*1024 + g*256 + j] : Bm[(k1-256)*1024 + g*256 + j];
  dst[id] = packbf2(v0, v1);
}

__global__ void pack_pairs(const float* __restrict__ src, u32* __restrict__ dst,
                           int Kpairs, int ncol){
  int id = blockIdx.x*256 + threadIdx.x;
  if (id >= Kpairs*ncol) return;
  int k2 = id / ncol, j = id - k2*ncol;
  dst[id] = packbf2(src[(2*k2)*ncol + j], src[(2*k2+1)*ncol + j]);
}

// MFMA B-fragment pack for 16x16x32_bf16, N=1024 (64 tiles), K rows.
// frag (tile t, kstep ks): lane l holds B[k = ks*32+(l>>4)*8+e][col = t*16+(l&15)]
// dst u32 index: ((t*KS+ks)*64 + l)*4 + e2   (e = 2*e2, 2*e2+1)
// row source: k<256 -> A[k*1024+col], else Bm[(k-256)*1024+col]
__global__ void pack_mfma(const float* __restrict__ A, const float* __restrict__ Bm,
                          u32* __restrict__ dst, int K){
  int id = blockIdx.x*256 + threadIdx.x;
  int KS = K >> 5;
  int tot = 64*KS*64*4;
  if (id >= tot) return;
  int e2 = id & 3;
  int l  = (id >> 2) & 63;
  int rest = id >> 8;
  int ks = rest % KS;
  int t  = rest / KS;
  int k  = ks*32 + (l>>4)*8 + e2*2;
  int col = t*16 + (l&15);
  float v0 = (k   < 256) ? A[k*1024 + col]       : Bm[(k-256)*1024 + col];
  float v1 = (k+1 < 256) ? A[(k+1)*1024 + col]   : Bm[(k+1-256)*1024 + col];
  dst[id] = packbf2(v0, v1);
}

__global__ void k_init_p(float* __restrict__ p0){
  int i = blockIdx.x*256 + threadIdx.x;
  if (i < ROWS) p0[i] = ((i % 81)==0) ? 1.0f : 0.0f;
}

// ---------------- K1: statement embedder + X0 precompute ----------------
__global__ __launch_bounds__(512) void k_stmt_x0(
    const float* __restrict__ ne, const float* __restrict__ stWx, const float* __restrict__ stb,
    const float* __restrict__ skWx, const float* __restrict__ skb, float4* __restrict__ X0){
  __shared__ float xv[2][256];
  __shared__ float hv[2][256];
  int r = threadIdx.x >> 8, j = threadIdx.x & 255;
  int bn = blockIdx.x*2 + r;                    // 0..639
  xv[r][j] = ne[bn*256 + j];
  __syncthreads();
  float a0=stb[j], a2=stb[512+j], a3=stb[768+j];
  for (int k=0;k<256;k++){
    float x = xv[r][k];
    const float* w = stWx + k*1024;
    a0 = fmaf(x, w[j], a0); a2 = fmaf(x, w[512+j], a2); a3 = fmaf(x, w[768+j], a3);
  }
  float c = sigf(a0)*tanh_fast(a2);
  float h = sigf(a3)*tanh_fast(c);
  hv[r][j] = h;
  __syncthreads();
  a0=stb[1024+j]; a2=stb[1536+j]; a3=stb[1792+j];
  const float* W1 = stWx + 256*1024;
  for (int k=0;k<256;k++){
    float x = hv[r][k];
    const float* w = W1 + k*1024;
    a0 = fmaf(x, w[j], a0); a2 = fmaf(x, w[512+j], a2); a3 = fmaf(x, w[768+j], a3);
  }
  c = sigf(a0)*tanh_fast(a2);
  h = sigf(a3)*tanh_fast(c);
  __syncthreads();
  xv[r][j] = h;           // stmt row
  __syncthreads();
  float b0=skb[j], b1g=skb[256+j], b2=skb[512+j], b3=skb[768+j];
  for (int k=0;k<256;k++){
    float x = xv[r][k];
    const float* w = skWx + k*1024;
    b0 = fmaf(x, w[j], b0);     b1g = fmaf(x, w[256+j], b1g);
    b2 = fmaf(x, w[512+j], b2); b3 = fmaf(x, w[768+j], b3);
  }
  X0[bn*256 + j] = make_float4(b0,b1g,b2,b3);
}

// ---------------- K3: skip-encoder chains (v4: MFMA) ---------------------
// grid = 80 blocks (one per s), 1024 threads (16 waves), all 8 batch rows.
//   matvec role: wave w owns cols [w*64,(w+1)*64) (4 tiles of 16);
//     A = 16 rows (8 real batches + 8 zero pad) of h, bf16 hi+lo planes in LDS;
//     B = weights pre-packed in fragment order, 1 dwordx4/lane per MFMA.
//     D (f32x4): col=lane&15, row=(lane>>4)*4+reg -> lanes 0-31 hold rows 0-7.
//   cell role: tid = rp*256+j handles rows rp and rp+4 (LSTM cell + LN).
#define RS0 264   // A-buf row stride (u16), layer0 K=256 (+8 pad: bank spread)
#define RS1 520   // layer1 K=512 (+8 pad)
__global__ __launch_bounds__(1024) void k_skip_chains(
    const float4* __restrict__ X0,
    const uint4* __restrict__ W0m, const uint4* __restrict__ W1m,
    const float* __restrict__ skb, const float* __restrict__ lnS, const float* __restrict__ lnB,
    float* __restrict__ skip){
  int s  = blockIdx.x;
  int tid = threadIdx.x;
  int w = tid >> 6, lane = tid & 63;
  int l15 = lane & 15, l4 = lane >> 4;
  int rp = tid >> 8, j = tid & 255;     // cell role: rows rp and rp+4
  __shared__ float part[8*1024];        // 32KB  D[row][col]
  __shared__ u16 A0h[16*RS0], A0l[16*RS0];  // layer0 A: h0_ln hi/lo
  __shared__ u16 A1h[16*RS1], A1l[16*RS1];  // layer1 A: [h0_raw | h1_ln] hi/lo
  __shared__ float red[4][16];
  for (int i=tid; i<16*RS0; i+=1024){ A0h[i]=0; A0l[i]=0; }
  for (int i=tid; i<16*RS1; i+=1024){ A1h[i]=0; A1l[i]=0; }
  float c0a=0.f, c1a=0.f, c0b=0.f, c1b=0.f;   // states rows rp / rp+4
  float s1b0=skb[1024+j], s1b1=skb[1280+j], s1b2=skb[1536+j], s1b3=skb[1792+j];
  float lS0=lnS[j], lS1=lnS[256+j], lS2=lnS[512+j], lS3=lnS[768+j];
  float lB0=lnB[j], lB1=lnB[256+j], lB2=lnB[512+j], lB3=lnB[768+j];
  const int aoff0 = l15*RS0 + l4*8;
  const int aoff1 = l15*RS1 + l4*8;
  __syncthreads();
  for (int idx=s; idx<80; idx++){
    float4 gxa = X0[(rp*80+idx)*256 + j];       // x-part gates, row rp
    float4 gxb = X0[((rp+4)*80+idx)*256 + j];   // row rp+4
    // ---- layer0 matvec: A0(h0_ln) x W0, K=256 (8 ksteps)
    f32x4 acc0={0,0,0,0}, acc1={0,0,0,0}, acc2={0,0,0,0}, acc3={0,0,0,0};
    #pragma unroll 4
    for (int ks=0; ks<8; ks++){
      bfv8 ah = *(const bfv8*)&A0h[aoff0 + ks*32];
      bfv8 al = *(const bfv8*)&A0l[aoff0 + ks*32];
      uint4 b0 = W0m[((w*4+0)*8 + ks)*64 + lane];
      uint4 b1 = W0m[((w*4+1)*8 + ks)*64 + lane];
      uint4 b2 = W0m[((w*4+2)*8 + ks)*64 + lane];
      uint4 b3 = W0m[((w*4+3)*8 + ks)*64 + lane];
      bfv8 v0=__builtin_bit_cast(bfv8,b0), v1=__builtin_bit_cast(bfv8,b1);
      bfv8 v2=__builtin_bit_cast(bfv8,b2), v3=__builtin_bit_cast(bfv8,b3);
      acc0=__builtin_amdgcn_mfma_f32_16x16x32_bf16(ah,v0,acc0,0,0,0);
      acc0=__builtin_amdgcn_mfma_f32_16x16x32_bf16(al,v0,acc0,0,0,0);
      acc1=__builtin_amdgcn_mfma_f32_16x16x32_bf16(ah,v1,acc1,0,0,0);
      acc1=__builtin_amdgcn_mfma_f32_16x16x32_bf16(al,v1,acc1,0,0,0);
      acc2=__builtin_amdgcn_mfma_f32_16x16x32_bf16(ah,v2,acc2,0,0,0);
      acc2=__builtin_amdgcn_mfma_f32_16x16x32_bf16(al,v2,acc2,0,0,0);
      acc3=__builtin_amdgcn_mfma_f32_16x16x32_bf16(ah,v3,acc3,0,0,0);
      acc3=__builtin_amdgcn_mfma_f32_16x16x32_bf16(al,v3,acc3,0,0,0);
    }
    if (lane < 32){
      int r0 = l4*4;
      #pragma unroll
      for (int q=0;q<4;q++){
        part[(r0+q)*1024 + w*64 +  0 + l15] = acc0[q];
        part[(r0+q)*1024 + w*64 + 16 + l15] = acc1[q];
        part[(r0+q)*1024 + w*64 + 32 + l15] = acc2[q];
        part[(r0+q)*1024 + w*64 + 48 + l15] = acc3[q];
      }
    }
    __syncthreads();                       // B1
    // ---- layer0 cell, rows rp and rp+4
    float h0na, h0nb;
    {
      float a0=gxa.x+part[rp*1024+j],     a1=gxa.y+part[rp*1024+256+j];
      float a2=gxa.z+part[rp*1024+512+j], a3=gxa.w+part[rp*1024+768+j];
      float ii=sigf(a0), ff=sigf(a1), gg=tanh_fast(a2), oo=sigf(a3);
      c0a = ff*c0a + ii*gg;
      h0na = oo*tanh_fast(c0a);
      u16 hi = f2bf(h0na);
      A1h[rp*RS1 + j] = hi;
      A1l[rp*RS1 + j] = f2bf(h0na - bf2f(hi));
    }
    {
      int rb = rp+4;
      float a0=gxb.x+part[rb*1024+j],     a1=gxb.y+part[rb*1024+256+j];
      float a2=gxb.z+part[rb*1024+512+j], a3=gxb.w+part[rb*1024+768+j];
      float ii=sigf(a0), ff=sigf(a1), gg=tanh_fast(a2), oo=sigf(a3);
      c0b = ff*c0b + ii*gg;
      h0nb = oo*tanh_fast(c0b);
      u16 hi = f2bf(h0nb);
      A1h[rb*RS1 + j] = hi;
      A1l[rb*RS1 + j] = f2bf(h0nb - bf2f(hi));
    }
    __syncthreads();                       // B2
    // ---- layer1 matvec: A1([h0_raw|h1_ln]) x W1, K=512 (16 ksteps)
    acc0=(f32x4){0,0,0,0}; acc1=(f32x4){0,0,0,0}; acc2=(f32x4){0,0,0,0}; acc3=(f32x4){0,0,0,0};
    #pragma unroll 4
    for (int ks=0; ks<16; ks++){
      bfv8 ah = *(const bfv8*)&A1h[aoff1 + ks*32];
      bfv8 al = *(const bfv8*)&A1l[aoff1 + ks*32];
      uint4 b0 = W1m[((w*4+0)*16 + ks)*64 + lane];
      uint4 b1 = W1m[((w*4+1)*16 + ks)*64 + lane];
      uint4 b2 = W1m[((w*4+2)*16 + ks)*64 + lane];
      uint4 b3 = W1m[((w*4+3)*16 + ks)*64 + lane];
      bfv8 v0=__builtin_bit_cast(bfv8,b0), v1=__builtin_bit_cast(bfv8,b1);
      bfv8 v2=__builtin_bit_cast(bfv8,b2), v3=__builtin_bit_cast(bfv8,b3);
      acc0=__builtin_amdgcn_mfma_f32_16x16x32_bf16(ah,v0,acc0,0,0,0);
      acc0=__builtin_amdgcn_mfma_f32_16x16x32_bf16(al,v0,acc0,0,0,0);
      acc1=__builtin_amdgcn_mfma_f32_16x16x32_bf16(ah,v1,acc1,0,0,0);
      acc1=__builtin_amdgcn_mfma_f32_16x16x32_bf16(al,v1,acc1,0,0,0);
      acc2=__builtin_amdgcn_mfma_f32_16x16x32_bf16(ah,v2,acc2,0,0,0);
      acc2=__builtin_amdgcn_mfma_f32_16x16x32_bf16(al,v2,acc2,0,0,0);
      acc3=__builtin_amdgcn_mfma_f32_16x16x32_bf16(ah,v3,acc3,0,0,0);
      acc3=__builtin_amdgcn_mfma_f32_16x16x32_bf16(al,v3,acc3,0,0,0);
    }
    if (lane < 32){
      int r0 = l4*4;
      #pragma unroll
      for (int q=0;q<4;q++){
        part[(r0+q)*1024 + w*64 +  0 + l15] = acc0[q];
        part[(r0+q)*1024 + w*64 + 16 + l15] = acc1[q];
        part[(r0+q)*1024 + w*64 + 32 + l15] = acc2[q];
        part[(r0+q)*1024 + w*64 + 48 + l15] = acc3[q];
      }
    }
    __syncthreads();                       // B3
    // ---- layer1 cell + LN, rows rp and rp+4
    float h1na, h1nb;
    {
      float a0=s1b0+part[rp*1024+j],     a1=s1b1+part[rp*1024+256+j];
      float a2=s1b2+part[rp*1024+512+j], a3=s1b3+part[rp*1024+768+j];
      float ii=sigf(a0), ff=sigf(a1), gg=tanh_fast(a2), oo=sigf(a3);
      c1a = ff*c1a + ii*gg;
      h1na = oo*tanh_fast(c1a);
      skip[((rp*81 + s)*81 + (idx+1))*256 + j] = h1na;
    }
    {
      int rb = rp+4;
      float a0=s1b0+part[rb*1024+j],     a1=s1b1+part[rb*1024+256+j];
      float a2=s1b2+part[rb*1024+512+j], a3=s1b3+part[rb*1024+768+j];
      float ii=sigf(a0), ff=sigf(a1), gg=tanh_fast(a2), oo=sigf(a3);
      c1b = ff*c1b + ii*gg;
      h1nb = oo*tanh_fast(c1b);
      skip[((rb*81 + s)*81 + (idx+1))*256 + j] = h1nb;
    }
    // ---- LayerNorm over concat(c0,h0n,c1,h1n) per row (1024 elems)
    float sm0 = c0a + h0na + c1a + h1na;
    float sq0 = c0a*c0a + h0na*h0na + c1a*c1a + h1na*h1na;
    float sm1 = c0b + h0nb + c1b + h1nb;
    float sq1 = c0b*c0b + h0nb*h0nb + c1b*c1b + h1nb*h1nb;
    #pragma unroll
    for (int off=32; off; off>>=1){
      sm0 += __shfl_xor(sm0, off); sq0 += __shfl_xor(sq0, off);
      sm1 += __shfl_xor(sm1, off); sq1 += __shfl_xor(sq1, off);
    }
    int wq = j >> 6;
    if ((j & 63) == 0){
      red[rp][wq*4+0]=sm0; red[rp][wq*4+1]=sq0;
      red[rp][wq*4+2]=sm1; red[rp][wq*4+3]=sq1;
    }
    __syncthreads();                       // B4
    sm0 = red[rp][0]+red[rp][4]+red[rp][8]+red[rp][12];
    sq0 = red[rp][1]+red[rp][5]+red[rp][9]+red[rp][13];
    sm1 = red[rp][2]+red[rp][6]+red[rp][10]+red[rp][14];
    sq1 = red[rp][3]+red[rp][7]+red[rp][11]+red[rp][15];
    {
      float mu = sm0 * (1.0f/1024.0f);
      float var = sq0 * (1.0f/1024.0f) - mu*mu;
      float rstd = rsqrtf(var + 1e-6f);
      c0a = (c0a - mu)*rstd*lS0 + lB0;
      float h0ln = (h0na - mu)*rstd*lS1 + lB1;
      c1a = (c1a - mu)*rstd*lS2 + lB2;
      float h1ln = (h1na - mu)*rstd*lS3 + lB3;
      u16 hi = f2bf(h0ln);
      A0h[rp*RS0 + j] = hi; A0l[rp*RS0 + j] = f2bf(h0ln - bf2f(hi));
      hi = f2bf(h1ln);
      A1h[rp*RS1 + 256 + j] = hi; A1l[rp*RS1 + 256 + j] = f2bf(h1ln - bf2f(hi));
    }
    {
      int rb = rp+4;
      float mu = sm1 * (1.0f/1024.0f);
      float var = sq1 * (1.0f/1024.0f) - mu*mu;
      float rstd = rsqrtf(var + 1e-6f);
      c0b = (c0b - mu)*rstd*lS0 + lB0;
      float h0ln = (h0nb - mu)*rstd*lS1 + lB1;
      c1b = (c1b - mu)*rstd*lS2 + lB2;
      float h1ln = (h1nb - mu)*rstd*lS3 + lB3;
      u16 hi = f2bf(h0ln);
      A0h[rb*RS0 + j] = hi; A0l[rb*RS0 + j] = f2bf(h0ln - bf2f(hi));
      hi = f2bf(h1ln);
      A1h[rb*RS1 + 256 + j] = hi; A1l[rb*RS1 + 256 + j] = f2bf(h1ln - bf2f(hi));
    }
    __syncthreads();                       // B5
  }
}

// ---------------- K4: keys = skip @ ws + bs  (bf16 out) ------------------
__global__ __launch_bounds__(256) void k_keys(const float* __restrict__ skip,
    const u32* __restrict__ wspk, const float* __restrict__ bs, u16* __restrict__ keys){
  __shared__ float skr[8][256];
  int tid = threadIdx.x;
  int bn = blockIdx.x;
  float bsv = bs[tid];
  const float4* sk4 = (const float4*)skip;
  for (int m0=0; m0<81; m0+=8){
    int mc = (81-m0 < 8) ? (81-m0) : 8;
    for (int i=tid; i<mc*64; i+=256){
      int mm = i>>6, kk = i&63;
      float4 v = sk4[(bn*81 + m0 + mm)*64 + kk];
      skr[mm][4*kk+0]=v.x; skr[mm][4*kk+1]=v.y; skr[mm][4*kk+2]=v.z; skr[mm][4*kk+3]=v.w;
    }
    __syncthreads();
    v2f acc[8];
    #pragma unroll
    for (int qq=0;qq<8;qq++) acc[qq]=(v2f){0.f,0.f};
    for (int k2=0;k2<128;k2++){
      v2f w2 = unpk(wspk[k2*256+tid]);
      #pragma unroll
      for (int qq=0;qq<8;qq++){
        v2f sv = *(const v2f*)&skr[qq][2*k2];
        acc[qq] += sv*w2;
      }
    }
    for (int qq=0;qq<mc;qq++) keys[(bn*81+m0+qq)*256+tid] = f2bf(acc[qq].x+acc[qq].y+bsv);
    __syncthreads();
  }
}

// ---------------- Kb: fused q + logits -> softmax -> t -------------------
// mode 0: only m==1; mode 1: m>n || m==80; mode 2: only m==80
__global__ __launch_bounds__(256) void k_attn(
    const float* __restrict__ c0g, const float* __restrict__ h0g,
    const float* __restrict__ c1g, const float* __restrict__ h1g,
    const u32* __restrict__ wkp, const float* __restrict__ bk,
    const u16* __restrict__ keys, const float* __restrict__ w1,
    const float* __restrict__ pcur, float* __restrict__ t, int mode){
  int bn = blockIdx.x; int n = bn % 81;
  int tid = threadIdx.x;
  float pv = pcur[bn];
  if (pv == 0.0f){
    if (tid < 81) t[bn*81 + tid] = 0.0f;
    return;
  }
  __shared__ float hc[1024];
  __shared__ float qv[256];
  __shared__ float lg[81];
  hc[tid]      = c0g[bn*256+tid];
  hc[256+tid]  = h0g[bn*256+tid];
  hc[512+tid]  = c1g[bn*256+tid];
  hc[768+tid]  = h1g[bn*256+tid];
  if (tid < 81) lg[tid] = -3e38f;
  __syncthreads();
  v2f A = {bk[tid], 0.f};
  #pragma unroll 8
  for (int k2=0;k2<512;k2++){
    v2f hp = *(const v2f*)&hc[2*k2];
    A += hp*unpk(wkp[k2*256+tid]);
  }
  qv[tid] = A.x + A.y;
  __syncthreads();
  int lane = tid & 63, wv = tid >> 6;
  float w1v0 = w1[lane], w1v1 = w1[64+lane], w1v2 = w1[128+lane], w1v3 = w1[192+lane];
  for (int m = wv; m < 81; m += 4){
    bool um = (mode==0) ? (m==1) : (mode==2) ? (m==80) : (m>n || m==80);
    if (!um) continue;
    const u16* kr = keys + (bn*81+m)*256;
    float acc;
    acc  = tanh_fast(qv[lane]     + bf2f(kr[lane]))     * w1v0;
    acc += tanh_fast(qv[64+lane]  + bf2f(kr[64+lane]))  * w1v1;
    acc += tanh_fast(qv[128+lane] + bf2f(kr[128+lane])) * w1v2;
    acc += tanh_fast(qv[192+lane] + bf2f(kr[192+lane])) * w1v3;
    #pragma unroll
    for (int off=32; off; off>>=1) acc += __shfl_xor(acc, off);
    if (lane==0) lg[m] = acc;      // b1 omitted: softmax-invariant
  }
  __syncthreads();
  if (tid < 64){
    float v1 = lg[tid];
    float v2 = (tid<17) ? lg[64+tid] : -3e38f;
    float mx = fmaxf(v1, v2);
    #pragma unroll
    for (int off=32; off; off>>=1) mx = fmaxf(mx, __shfl_xor(mx, off));
    float e1 = __expf(v1-mx);
    float e2 = (tid<17) ? __expf(v2-mx) : 0.0f;
    float ssum = e1+e2;
    #pragma unroll
    for (int off=32; off; off>>=1) ssum += __shfl_xor(ssum, off);
    float sc = pv / ssum;
    t[bn*81 + tid] = e1*sc;
    if (tid<17) t[bn*81 + 64+tid] = e2*sc;
  }
}

// ---------------- Kc: x_in/prop einsums + ex-LSTM step + new_p -----------
__global__ __launch_bounds__(1024) void k_update(
    const float* __restrict__ t, const float* __restrict__ skip,
    const float* __restrict__ c0i, const float* __restrict__ h0i,
    const float* __restrict__ c1i, const float* __restrict__ h1i,
    const uint4* __restrict__ WA, const uint4* __restrict__ WB,
    const float* __restrict__ exb,
    float* __restrict__ c0o, float* __restrict__ h0o,
    float* __restrict__ c1o, float* __restrict__ h1o,
    float* __restrict__ pnext){
  int rr = threadIdx.x >> 8, j = threadIdx.x & 255;
  int row = blockIdx.x*4 + rr;
  int b = row / 81, m = row - b*81;
  __shared__ float tcol[4][81];
  __shared__ float xh[4][512];
  if (j < 81) tcol[rr][j] = t[(b*81 + j)*81 + m];
  __syncthreads();
  float xa=0.f, c0p=0.f, h0p=0.f, c1p=0.f, h1p=0.f, ts=0.f;
  for (int n=0;n<81;n++){
    float tv = tcol[rr][n];
    ts += tv;
    if (tv != 0.0f){
      xa  = fmaf(tv, skip[((b*81+n)*81 + m)*256 + j], xa);
      int st = (b*81+n)*256 + j;
      c0p = fmaf(tv, c0i[st], c0p);
      h0p = fmaf(tv, h0i[st], h0p);
      c1p = fmaf(tv, c1i[st], c1p);
      h1p = fmaf(tv, h1i[st], h1p);
    }
  }
  bool alive = (ts != 0.0f);
  float inv = 1.0f/(ts + 1e-7f);
  xa*=inv; c0p*=inv; h0p*=inv; c1p*=inv; h1p*=inv;
  if (j==0) pnext[row] = ts;
  xh[rr][j] = xa; xh[rr][256+j] = h0p;
  __syncthreads();
  float c0n=0.f, h0n=0.f;
  if (alive){
    v2f A0={exb[j],0.f}, A1={exb[256+j],0.f}, A2={exb[512+j],0.f}, A3={exb[768+j],0.f};
    #pragma unroll 8
    for (int k2=0;k2<256;k2++){
      v2f hp = *(const v2f*)&xh[rr][2*k2];
      uint4 w = WA[k2*256+j];
      A0 += hp*unpk(w.x); A1 += hp*unpk(w.y);
      A2 += hp*unpk(w.z); A3 += hp*unpk(w.w);
    }
    float a0=A0.x+A0.y, a1=A1.x+A1.y, a2=A2.x+A2.y, a3=A3.x+A3.y;
    c0n = sigf(a1)*c0p + sigf(a0)*tanh_fast(a2);
    h0n = sigf(a3)*tanh_fast(c0n);
  }
  __syncthreads();
  xh[rr][j] = h0n; xh[rr][256+j] = h1p;
  __syncthreads();
  if (alive){
    v2f A0={exb[1024+j],0.f}, A1={exb[1280+j],0.f}, A2={exb[1536+j],0.f}, A3={exb[1792+j],0.f};
    #pragma unroll 8
    for (int k2=0;k2<256;k2++){
      v2f hp = *(const v2f*)&xh[rr][2*k2];
      uint4 w = WB[k2*256+j];
      A0 += hp*unpk(w.x); A1 += hp*unpk(w.y);
      A2 += hp*unpk(w.z); A3 += hp*unpk(w.w);
    }
    float a0=A0.x+A0.y, a1=A1.x+A1.y, a2=A2.x+A2.y, a3=A3.x+A3.y;
    float c1n = sigf(a1)*c1p + sigf(a0)*tanh_fast(a2);
    float h1n = sigf(a3)*tanh_fast(c1n);
    int o = row*256 + j;
    c0o[o]=c0n; h0o[o]=h0n; c1o[o]=c1n; h1o[o]=h1n;
  }
}

// ---------------- K6: out = h_exit @ wo + bo -----------------------------
__global__ __launch_bounds__(256) void k_out(
    const float* __restrict__ h1f, const int* __restrict__ exitIdx,
    const float* __restrict__ wo, const float* __restrict__ bo, float* __restrict__ out){
  __shared__ float hv[8][256];
  int tid = threadIdx.x;
  for (int i = tid; i < 2048; i += 256){
    int b = i >> 8, k = i & 255;
    hv[b][k] = h1f[(b*81 + exitIdx[b])*256 + k];
  }
  __syncthreads();
  int v = blockIdx.x*256 + tid;
  if (v >= 30000) return;
  float acc[8];
  #pragma unroll
  for (int b=0;b<8;b++) acc[b] = bo[v];
  for (int k=0;k<256;k++){
    float w = wo[k*30000 + v];
    #pragma unroll
    for (int b=0;b<8;b++) acc[b] = fmaf(hv[b][k], w, acc[b]);
  }
  #pragma unroll
  for (int b=0;b<8;b++) out[b*30000+v] = acc[b];
}

// ---------------- launch --------------------------------------------------
extern "C" void kernel_launch(void* const* d_in, const int* in_sizes, int n_in,
                              void* d_out, int out_size, void* d_ws, size_t ws_size,
                              hipStream_t stream){
  (void)in_sizes; (void)n_in; (void)out_size;
  const float* ne    = (const float*)d_in[0];
  const int*   exitI = (const int*)d_in[10];
  const float* stWx  = (const float*)d_in[12];
  const float* stb   = (const float*)d_in[14];
  const float* skWx  = (const float*)d_in[15];
  const float* skWh  = (const float*)d_in[16];
  const float* skb   = (const float*)d_in[17];
  const float* lnS   = (const float*)d_in[18];
  const float* lnB   = (const float*)d_in[19];
  const float* exWx  = (const float*)d_in[20];
  const float* exWh  = (const float*)d_in[21];
  const float* exb   = (const float*)d_in[22];
  const float* wk    = (const float*)d_in[23];
  const float* bk    = (const float*)d_in[24];
  const float* wsm   = (const float*)d_in[25];
  const float* bs    = (const float*)d_in[26];
  const float* w1    = (const float*)d_in[27];
  const float* wo    = (const float*)d_in[29];
  const float* bo    = (const float*)d_in[30];
  float* out = (float*)d_out;

  char* w = (char*)d_ws;
  size_t off = 0;
  auto alloc = [&](size_t bytes)->char*{
    char* p = w + off; off += (bytes + 255) & ~size_t(255); return p;
  };
  float4* X0   = (float4*)alloc((size_t)640*256*16);
  u32* W0m     = (u32*)alloc((size_t)131072*4);          // MFMA frag, K=256
  u32* W1m     = (u32*)alloc((size_t)262144*4);          // MFMA frag, K=512
  u32* WApk    = (u32*)alloc((size_t)256*1024*4);
  u32* WBpk    = (u32*)alloc((size_t)256*1024*4);
  u32* wkp     = (u32*)alloc((size_t)512*256*4);
  u32* wspk    = (u32*)alloc((size_t)128*256*4);
  float* skip  = (float*)alloc((size_t)8*81*81*256*4);   // fp32
  u16* keys    = (u16*)alloc((size_t)8*81*81*256*2);     // bf16
  float* tb    = (float*)alloc((size_t)ROWS*81*4);
  float* p0    = (float*)alloc(ROWS*4);
  float* p1    = (float*)alloc(ROWS*4);
  float* stA   = (float*)alloc((size_t)4*ROWS*256*4);
  float* stB   = (float*)alloc((size_t)4*ROWS*256*4);
  if (off > ws_size) return;   // workspace too small — surfaces as absmax fail

  const size_t ST = (size_t)ROWS*256;
  float *A_c0=stA, *A_h0=stA+ST, *A_c1=stA+2*ST, *A_h1=stA+3*ST;
  float *B_c0=stB, *B_h0=stB+ST, *B_c1=stB+2*ST, *B_h1=stB+3*ST;

  hipMemsetAsync(skip, 0, (size_t)8*81*81*256*4, stream);
  hipMemsetAsync(stA, 0, (size_t)4*ROWS*256*4, stream);
  hipMemsetAsync(stB, 0, (size_t)4*ROWS*256*4, stream);
  k_init_p<<<3,256,0,stream>>>(p0);

  pack_mfma<<<512, 256, 0, stream>>>(skWh, skWh, W0m, 256);                        // Wh0
  pack_mfma<<<1024,256, 0, stream>>>(skWx+256*1024, skWh+256*1024, W1m, 512);      // [Wx1;Wh1]
  pack_gates<<<1024,256, 0, stream>>>(exWx, exWh, WApk, 512);                      // [exWx0;exWh0]
  pack_gates<<<1024,256, 0, stream>>>(exWx+256*1024, exWh+256*1024, WBpk, 512);    // [exWx1;exWh1]
  pack_pairs<<<512, 256, 0, stream>>>(wk, wkp, 512, 256);
  pack_pairs<<<128, 256, 0, stream>>>(wsm, wspk, 128, 256);

  k_stmt_x0<<<320, 512, 0, stream>>>(ne, stWx, stb, skWx, skb, X0);
  k_skip_chains<<<80, 1024, 0, stream>>>(X0, (const uint4*)W0m, (const uint4*)W1m,
                                         skb, lnS, lnB, skip);
  k_keys<<<648, 256, 0, stream>>>(skip, wspk, bs, keys);

  float* pc = p0; float* pn = p1;
  for (int s=0; s<8; s++){
    float *ic0,*ih0,*ic1,*ih1,*oc0,*oh0,*oc1,*oh1;
    if ((s & 1) == 0){ ic0=A_c0; ih0=A_h0; ic1=A_c1; ih1=A_h1; oc0=B_c0; oh0=B_h0; oc1=B_c1; oh1=B_h1; }
    else             { ic0=B_c0; ih0=B_h0; ic1=B_c1; ih1=B_h1; oc0=A_c0; oh0=A_h0; oc1=A_c1; oh1=A_h1; }
    int mode = (s==0) ? 0 : ((s==7) ? 2 : 1);
    k_attn<<<648, 256, 0, stream>>>(ic0, ih0, ic1, ih1, wkp, bk, keys, w1, pc, tb, mode);
    k_update<<<162, 1024, 0, stream>>>(tb, skip, ic0, ih0, ic1, ih1,
                                       (const uint4*)WApk, (const uint4*)WBpk, exb,
                                       oc0, oh0, oc1, oh1, pn);
    float* tmp = pc; pc = pn; pn = tmp;
  }
  // final states are in buffer A (step 7 writes A)
  k_out<<<(30000+255)/256, 256, 0, stream>>>(A_h1, exitI, wo, bo, out);
}

// Round 4
// 2267.344 us; speedup vs baseline: 1.8031x; 1.2082x over previous
//
#include <hip/hip_runtime.h>

typedef unsigned int  u32;
typedef unsigned short u16;
typedef float v2f __attribute__((ext_vector_type(2)));
typedef __attribute__((ext_vector_type(8))) short bfv8;   // 8 bf16 = 4 VGPR
typedef __attribute__((ext_vector_type(4))) float f32x4;

// B=8, NS=80, NN=81, H=256, L=2, STEPS=8, VOCAB=30000
#define ROWS 648          // B*NN

__device__ __forceinline__ float sigf(float x){ return 1.0f/(1.0f+__expf(-x)); }
__device__ __forceinline__ float tanh_fast(float x){
  float e = __expf(-2.0f*fabsf(x));
  float r = (1.0f-e)/(1.0f+e);
  return copysignf(r,x);
}
__device__ __forceinline__ u16 f2bf(float f){        // RTNE f32->bf16
  u32 u = __float_as_uint(f);
  u += 0x7FFFu + ((u>>16)&1u);
  return (u16)(u>>16);
}
__device__ __forceinline__ u32 packbf2(float lo, float hi){
  return (u32)f2bf(lo) | ((u32)f2bf(hi)<<16);
}
__device__ __forceinline__ float bf2f(u16 v){ return __uint_as_float(((u32)v)<<16); }
__device__ __forceinline__ float bflo(u32 u){ return __uint_as_float(u<<16); }
__device__ __forceinline__ float bfhi(u32 u){ return __uint_as_float(u & 0xFFFF0000u); }
__device__ __forceinline__ v2f unpk(u32 w){
  v2f r; r.x = bflo(w); r.y = bfhi(w); return r;
}

// ---------------- weight packing ----------------------------------------
__global__ void pack_pairs(const float* __restrict__ src, u32* __restrict__ dst,
                           int Kpairs, int ncol){
  int id = blockIdx.x*256 + threadIdx.x;
  if (id >= Kpairs*ncol) return;
  int k2 = id / ncol, j = id - k2*ncol;
  dst[id] = packbf2(src[(2*k2)*ncol + j], src[(2*k2+1)*ncol + j]);
}

// MFMA B-fragment pack for 16x16x32_bf16, N=1024 (64 tiles), K rows.
// frag (tile t, kstep ks): lane l holds B[k = ks*32+(l>>4)*8+e][col = t*16+(l&15)]
// dst u32 index: ((t*KS+ks)*64 + l)*4 + e2   (e = 2*e2, 2*e2+1)
// row source: k<256 -> A[k*1024+col], else Bm[(k-256)*1024+col]
__global__ void pack_mfma(const float* __restrict__ A, const float* __restrict__ Bm,
                          u32* __restrict__ dst, int K){
  int id = blockIdx.x*256 + threadIdx.x;
  int KS = K >> 5;
  int tot = 64*KS*64*4;
  if (id >= tot) return;
  int e2 = id & 3;
  int l  = (id >> 2) & 63;
  int rest = id >> 8;
  int ks = rest % KS;
  int t  = rest / KS;
  int k  = ks*32 + (l>>4)*8 + e2*2;
  int col = t*16 + (l&15);
  float v0 = (k   < 256) ? A[k*1024 + col]       : Bm[(k-256)*1024 + col];
  float v1 = (k+1 < 256) ? A[(k+1)*1024 + col]   : Bm[(k+1-256)*1024 + col];
  dst[id] = packbf2(v0, v1);
}

__global__ void k_init_p(float* __restrict__ p0){
  int i = blockIdx.x*256 + threadIdx.x;
  if (i < ROWS) p0[i] = ((i % 81)==0) ? 1.0f : 0.0f;
}

// ---------------- K1: statement embedder + X0 precompute ----------------
__global__ __launch_bounds__(512) void k_stmt_x0(
    const float* __restrict__ ne, const float* __restrict__ stWx, const float* __restrict__ stb,
    const float* __restrict__ skWx, const float* __restrict__ skb, float4* __restrict__ X0){
  __shared__ float xv[2][256];
  __shared__ float hv[2][256];
  int r = threadIdx.x >> 8, j = threadIdx.x & 255;
  int bn = blockIdx.x*2 + r;                    // 0..639
  xv[r][j] = ne[bn*256 + j];
  __syncthreads();
  float a0=stb[j], a2=stb[512+j], a3=stb[768+j];
  for (int k=0;k<256;k++){
    float x = xv[r][k];
    const float* w = stWx + k*1024;
    a0 = fmaf(x, w[j], a0); a2 = fmaf(x, w[512+j], a2); a3 = fmaf(x, w[768+j], a3);
  }
  float c = sigf(a0)*tanh_fast(a2);
  float h = sigf(a3)*tanh_fast(c);
  hv[r][j] = h;
  __syncthreads();
  a0=stb[1024+j]; a2=stb[1536+j]; a3=stb[1792+j];
  const float* W1 = stWx + 256*1024;
  for (int k=0;k<256;k++){
    float x = hv[r][k];
    const float* w = W1 + k*1024;
    a0 = fmaf(x, w[j], a0); a2 = fmaf(x, w[512+j], a2); a3 = fmaf(x, w[768+j], a3);
  }
  c = sigf(a0)*tanh_fast(a2);
  h = sigf(a3)*tanh_fast(c);
  __syncthreads();
  xv[r][j] = h;           // stmt row
  __syncthreads();
  float b0=skb[j], b1g=skb[256+j], b2=skb[512+j], b3=skb[768+j];
  for (int k=0;k<256;k++){
    float x = xv[r][k];
    const float* w = skWx + k*1024;
    b0 = fmaf(x, w[j], b0);     b1g = fmaf(x, w[256+j], b1g);
    b2 = fmaf(x, w[512+j], b2); b3 = fmaf(x, w[768+j], b3);
  }
  X0[bn*256 + j] = make_float4(b0,b1g,b2,b3);
}

// ---------------- K3: skip-encoder chains (MFMA) -------------------------
// NOTE: M-tile = 16 rows where rows 8-15 are ZERO PADDING; store of D rows
// 0-7 via lanes<32 is intentional here (unlike k_exlstm!).
#define RS0 264   // A-buf row stride (u16), layer0 K=256 (+8 pad)
#define RS1 520   // layer1 K=512 (+8 pad)
__global__ __launch_bounds__(1024) void k_skip_chains(
    const float4* __restrict__ X0,
    const uint4* __restrict__ W0m, const uint4* __restrict__ W1m,
    const float* __restrict__ skb, const float* __restrict__ lnS, const float* __restrict__ lnB,
    float* __restrict__ skip){
  int s  = blockIdx.x;
  int tid = threadIdx.x;
  int w = tid >> 6, lane = tid & 63;
  int l15 = lane & 15, l4 = lane >> 4;
  int rp = tid >> 8, j = tid & 255;     // cell role: rows rp and rp+4
  __shared__ float part[8*1024];        // 32KB  D[row][col]
  __shared__ u16 A0h[16*RS0], A0l[16*RS0];  // layer0 A: h0_ln hi/lo
  __shared__ u16 A1h[16*RS1], A1l[16*RS1];  // layer1 A: [h0_raw | h1_ln] hi/lo
  __shared__ float red[4][16];
  for (int i=tid; i<16*RS0; i+=1024){ A0h[i]=0; A0l[i]=0; }
  for (int i=tid; i<16*RS1; i+=1024){ A1h[i]=0; A1l[i]=0; }
  float c0a=0.f, c1a=0.f, c0b=0.f, c1b=0.f;   // states rows rp / rp+4
  float s1b0=skb[1024+j], s1b1=skb[1280+j], s1b2=skb[1536+j], s1b3=skb[1792+j];
  float lS0=lnS[j], lS1=lnS[256+j], lS2=lnS[512+j], lS3=lnS[768+j];
  float lB0=lnB[j], lB1=lnB[256+j], lB2=lnB[512+j], lB3=lnB[768+j];
  const int aoff0 = l15*RS0 + l4*8;
  const int aoff1 = l15*RS1 + l4*8;
  __syncthreads();
  for (int idx=s; idx<80; idx++){
    float4 gxa = X0[(rp*80+idx)*256 + j];       // x-part gates, row rp
    float4 gxb = X0[((rp+4)*80+idx)*256 + j];   // row rp+4
    // ---- layer0 matvec: A0(h0_ln) x W0, K=256 (8 ksteps)
    f32x4 acc0={0,0,0,0}, acc1={0,0,0,0}, acc2={0,0,0,0}, acc3={0,0,0,0};
    #pragma unroll 4
    for (int ks=0; ks<8; ks++){
      bfv8 ah = *(const bfv8*)&A0h[aoff0 + ks*32];
      bfv8 al = *(const bfv8*)&A0l[aoff0 + ks*32];
      uint4 b0 = W0m[((w*4+0)*8 + ks)*64 + lane];
      uint4 b1 = W0m[((w*4+1)*8 + ks)*64 + lane];
      uint4 b2 = W0m[((w*4+2)*8 + ks)*64 + lane];
      uint4 b3 = W0m[((w*4+3)*8 + ks)*64 + lane];
      bfv8 v0=__builtin_bit_cast(bfv8,b0), v1=__builtin_bit_cast(bfv8,b1);
      bfv8 v2=__builtin_bit_cast(bfv8,b2), v3=__builtin_bit_cast(bfv8,b3);
      acc0=__builtin_amdgcn_mfma_f32_16x16x32_bf16(ah,v0,acc0,0,0,0);
      acc0=__builtin_amdgcn_mfma_f32_16x16x32_bf16(al,v0,acc0,0,0,0);
      acc1=__builtin_amdgcn_mfma_f32_16x16x32_bf16(ah,v1,acc1,0,0,0);
      acc1=__builtin_amdgcn_mfma_f32_16x16x32_bf16(al,v1,acc1,0,0,0);
      acc2=__builtin_amdgcn_mfma_f32_16x16x32_bf16(ah,v2,acc2,0,0,0);
      acc2=__builtin_amdgcn_mfma_f32_16x16x32_bf16(al,v2,acc2,0,0,0);
      acc3=__builtin_amdgcn_mfma_f32_16x16x32_bf16(ah,v3,acc3,0,0,0);
      acc3=__builtin_amdgcn_mfma_f32_16x16x32_bf16(al,v3,acc3,0,0,0);
    }
    if (lane < 32){
      int r0 = l4*4;
      #pragma unroll
      for (int q=0;q<4;q++){
        part[(r0+q)*1024 + w*64 +  0 + l15] = acc0[q];
        part[(r0+q)*1024 + w*64 + 16 + l15] = acc1[q];
        part[(r0+q)*1024 + w*64 + 32 + l15] = acc2[q];
        part[(r0+q)*1024 + w*64 + 48 + l15] = acc3[q];
      }
    }
    __syncthreads();                       // B1
    // ---- layer0 cell, rows rp and rp+4
    float h0na, h0nb;
    {
      float a0=gxa.x+part[rp*1024+j],     a1=gxa.y+part[rp*1024+256+j];
      float a2=gxa.z+part[rp*1024+512+j], a3=gxa.w+part[rp*1024+768+j];
      float ii=sigf(a0), ff=sigf(a1), gg=tanh_fast(a2), oo=sigf(a3);
      c0a = ff*c0a + ii*gg;
      h0na = oo*tanh_fast(c0a);
      u16 hi = f2bf(h0na);
      A1h[rp*RS1 + j] = hi;
      A1l[rp*RS1 + j] = f2bf(h0na - bf2f(hi));
    }
    {
      int rb = rp+4;
      float a0=gxb.x+part[rb*1024+j],     a1=gxb.y+part[rb*1024+256+j];
      float a2=gxb.z+part[rb*1024+512+j], a3=gxb.w+part[rb*1024+768+j];
      float ii=sigf(a0), ff=sigf(a1), gg=tanh_fast(a2), oo=sigf(a3);
      c0b = ff*c0b + ii*gg;
      h0nb = oo*tanh_fast(c0b);
      u16 hi = f2bf(h0nb);
      A1h[rb*RS1 + j] = hi;
      A1l[rb*RS1 + j] = f2bf(h0nb - bf2f(hi));
    }
    __syncthreads();                       // B2
    // ---- layer1 matvec: A1([h0_raw|h1_ln]) x W1, K=512 (16 ksteps)
    acc0=(f32x4){0,0,0,0}; acc1=(f32x4){0,0,0,0}; acc2=(f32x4){0,0,0,0}; acc3=(f32x4){0,0,0,0};
    #pragma unroll 4
    for (int ks=0; ks<16; ks++){
      bfv8 ah = *(const bfv8*)&A1h[aoff1 + ks*32];
      bfv8 al = *(const bfv8*)&A1l[aoff1 + ks*32];
      uint4 b0 = W1m[((w*4+0)*16 + ks)*64 + lane];
      uint4 b1 = W1m[((w*4+1)*16 + ks)*64 + lane];
      uint4 b2 = W1m[((w*4+2)*16 + ks)*64 + lane];
      uint4 b3 = W1m[((w*4+3)*16 + ks)*64 + lane];
      bfv8 v0=__builtin_bit_cast(bfv8,b0), v1=__builtin_bit_cast(bfv8,b1);
      bfv8 v2=__builtin_bit_cast(bfv8,b2), v3=__builtin_bit_cast(bfv8,b3);
      acc0=__builtin_amdgcn_mfma_f32_16x16x32_bf16(ah,v0,acc0,0,0,0);
      acc0=__builtin_amdgcn_mfma_f32_16x16x32_bf16(al,v0,acc0,0,0,0);
      acc1=__builtin_amdgcn_mfma_f32_16x16x32_bf16(ah,v1,acc1,0,0,0);
      acc1=__builtin_amdgcn_mfma_f32_16x16x32_bf16(al,v1,acc1,0,0,0);
      acc2=__builtin_amdgcn_mfma_f32_16x16x32_bf16(ah,v2,acc2,0,0,0);
      acc2=__builtin_amdgcn_mfma_f32_16x16x32_bf16(al,v2,acc2,0,0,0);
      acc3=__builtin_amdgcn_mfma_f32_16x16x32_bf16(ah,v3,acc3,0,0,0);
      acc3=__builtin_amdgcn_mfma_f32_16x16x32_bf16(al,v3,acc3,0,0,0);
    }
    if (lane < 32){
      int r0 = l4*4;
      #pragma unroll
      for (int q=0;q<4;q++){
        part[(r0+q)*1024 + w*64 +  0 + l15] = acc0[q];
        part[(r0+q)*1024 + w*64 + 16 + l15] = acc1[q];
        part[(r0+q)*1024 + w*64 + 32 + l15] = acc2[q];
        part[(r0+q)*1024 + w*64 + 48 + l15] = acc3[q];
      }
    }
    __syncthreads();                       // B3
    // ---- layer1 cell + LN, rows rp and rp+4
    float h1na, h1nb;
    {
      float a0=s1b0+part[rp*1024+j],     a1=s1b1+part[rp*1024+256+j];
      float a2=s1b2+part[rp*1024+512+j], a3=s1b3+part[rp*1024+768+j];
      float ii=sigf(a0), ff=sigf(a1), gg=tanh_fast(a2), oo=sigf(a3);
      c1a = ff*c1a + ii*gg;
      h1na = oo*tanh_fast(c1a);
      skip[((rp*81 + s)*81 + (idx+1))*256 + j] = h1na;
    }
    {
      int rb = rp+4;
      float a0=s1b0+part[rb*1024+j],     a1=s1b1+part[rb*1024+256+j];
      float a2=s1b2+part[rb*1024+512+j], a3=s1b3+part[rb*1024+768+j];
      float ii=sigf(a0), ff=sigf(a1), gg=tanh_fast(a2), oo=sigf(a3);
      c1b = ff*c1b + ii*gg;
      h1nb = oo*tanh_fast(c1b);
      skip[((rb*81 + s)*81 + (idx+1))*256 + j] = h1nb;
    }
    // ---- LayerNorm over concat(c0,h0n,c1,h1n) per row (1024 elems)
    float sm0 = c0a + h0na + c1a + h1na;
    float sq0 = c0a*c0a + h0na*h0na + c1a*c1a + h1na*h1na;
    float sm1 = c0b + h0nb + c1b + h1nb;
    float sq1 = c0b*c0b + h0nb*h0nb + c1b*c1b + h1nb*h1nb;
    #pragma unroll
    for (int off=32; off; off>>=1){
      sm0 += __shfl_xor(sm0, off); sq0 += __shfl_xor(sq0, off);
      sm1 += __shfl_xor(sm1, off); sq1 += __shfl_xor(sq1, off);
    }
    int wq = j >> 6;
    if ((j & 63) == 0){
      red[rp][wq*4+0]=sm0; red[rp][wq*4+1]=sq0;
      red[rp][wq*4+2]=sm1; red[rp][wq*4+3]=sq1;
    }
    __syncthreads();                       // B4
    sm0 = red[rp][0]+red[rp][4]+red[rp][8]+red[rp][12];
    sq0 = red[rp][1]+red[rp][5]+red[rp][9]+red[rp][13];
    sm1 = red[rp][2]+red[rp][6]+red[rp][10]+red[rp][14];
    sq1 = red[rp][3]+red[rp][7]+red[rp][11]+red[rp][15];
    {
      float mu = sm0 * (1.0f/1024.0f);
      float var = sq0 * (1.0f/1024.0f) - mu*mu;
      float rstd = rsqrtf(var + 1e-6f);
      c0a = (c0a - mu)*rstd*lS0 + lB0;
      float h0ln = (h0na - mu)*rstd*lS1 + lB1;
      c1a = (c1a - mu)*rstd*lS2 + lB2;
      float h1ln = (h1na - mu)*rstd*lS3 + lB3;
      u16 hi = f2bf(h0ln);
      A0h[rp*RS0 + j] = hi; A0l[rp*RS0 + j] = f2bf(h0ln - bf2f(hi));
      hi = f2bf(h1ln);
      A1h[rp*RS1 + 256 + j] = hi; A1l[rp*RS1 + 256 + j] = f2bf(h1ln - bf2f(hi));
    }
    {
      int rb = rp+4;
      float mu = sm1 * (1.0f/1024.0f);
      float var = sq1 * (1.0f/1024.0f) - mu*mu;
      float rstd = rsqrtf(var + 1e-6f);
      c0b = (c0b - mu)*rstd*lS0 + lB0;
      float h0ln = (h0nb - mu)*rstd*lS1 + lB1;
      c1b = (c1b - mu)*rstd*lS2 + lB2;
      float h1ln = (h1nb - mu)*rstd*lS3 + lB3;
      u16 hi = f2bf(h0ln);
      A0h[rb*RS0 + j] = hi; A0l[rb*RS0 + j] = f2bf(h0ln - bf2f(hi));
      hi = f2bf(h1ln);
      A1h[rb*RS1 + 256 + j] = hi; A1l[rb*RS1 + 256 + j] = f2bf(h1ln - bf2f(hi));
    }
    __syncthreads();                       // B5
  }
}

// ---------------- K4: keys = skip @ ws + bs  (bf16 out) ------------------
__global__ __launch_bounds__(256) void k_keys(const float* __restrict__ skip,
    const u32* __restrict__ wspk, const float* __restrict__ bs, u16* __restrict__ keys){
  __shared__ float skr[8][256];
  int tid = threadIdx.x;
  int bn = blockIdx.x;
  float bsv = bs[tid];
  const float4* sk4 = (const float4*)skip;
  for (int m0=0; m0<81; m0+=8){
    int mc = (81-m0 < 8) ? (81-m0) : 8;
    for (int i=tid; i<mc*64; i+=256){
      int mm = i>>6, kk = i&63;
      float4 v = sk4[(bn*81 + m0 + mm)*64 + kk];
      skr[mm][4*kk+0]=v.x; skr[mm][4*kk+1]=v.y; skr[mm][4*kk+2]=v.z; skr[mm][4*kk+3]=v.w;
    }
    __syncthreads();
    v2f acc[8];
    #pragma unroll
    for (int qq=0;qq<8;qq++) acc[qq]=(v2f){0.f,0.f};
    for (int k2=0;k2<128;k2++){
      v2f w2 = unpk(wspk[k2*256+tid]);
      #pragma unroll
      for (int qq=0;qq<8;qq++){
        v2f sv = *(const v2f*)&skr[qq][2*k2];
        acc[qq] += sv*w2;
      }
    }
    for (int qq=0;qq<mc;qq++) keys[(bn*81+m0+qq)*256+tid] = f2bf(acc[qq].x+acc[qq].y+bsv);
    __syncthreads();
  }
}

// ---------------- Kb: fused q + logits -> softmax -> t -------------------
// mode 0: only m==1; mode 1: m>n || m==80; mode 2: only m==80
__global__ __launch_bounds__(256) void k_attn(
    const float* __restrict__ c0g, const float* __restrict__ h0g,
    const float* __restrict__ c1g, const float* __restrict__ h1g,
    const u32* __restrict__ wkp, const float* __restrict__ bk,
    const u16* __restrict__ keys, const float* __restrict__ w1,
    const float* __restrict__ pcur, float* __restrict__ t, int mode){
  int bn = blockIdx.x; int n = bn % 81;
  int tid = threadIdx.x;
  float pv = pcur[bn];
  if (pv == 0.0f){
    if (tid < 81) t[bn*81 + tid] = 0.0f;
    return;
  }
  __shared__ float hc[1024];
  __shared__ float qv[256];
  __shared__ float lg[81];
  hc[tid]      = c0g[bn*256+tid];
  hc[256+tid]  = h0g[bn*256+tid];
  hc[512+tid]  = c1g[bn*256+tid];
  hc[768+tid]  = h1g[bn*256+tid];
  if (tid < 81) lg[tid] = -3e38f;
  __syncthreads();
  v2f A = {bk[tid], 0.f};
  #pragma unroll 8
  for (int k2=0;k2<512;k2++){
    v2f hp = *(const v2f*)&hc[2*k2];
    A += hp*unpk(wkp[k2*256+tid]);
  }
  qv[tid] = A.x + A.y;
  __syncthreads();
  int lane = tid & 63, wv = tid >> 6;
  float w1v0 = w1[lane], w1v1 = w1[64+lane], w1v2 = w1[128+lane], w1v3 = w1[192+lane];
  for (int m = wv; m < 81; m += 4){
    bool um = (mode==0) ? (m==1) : (mode==2) ? (m==80) : (m>n || m==80);
    if (!um) continue;
    const u16* kr = keys + (bn*81+m)*256;
    float acc;
    acc  = tanh_fast(qv[lane]     + bf2f(kr[lane]))     * w1v0;
    acc += tanh_fast(qv[64+lane]  + bf2f(kr[64+lane]))  * w1v1;
    acc += tanh_fast(qv[128+lane] + bf2f(kr[128+lane])) * w1v2;
    acc += tanh_fast(qv[192+lane] + bf2f(kr[192+lane])) * w1v3;
    #pragma unroll
    for (int off=32; off; off>>=1) acc += __shfl_xor(acc, off);
    if (lane==0) lg[m] = acc;      // b1 omitted: softmax-invariant
  }
  __syncthreads();
  if (tid < 64){
    float v1 = lg[tid];
    float v2 = (tid<17) ? lg[64+tid] : -3e38f;
    float mx = fmaxf(v1, v2);
    #pragma unroll
    for (int off=32; off; off>>=1) mx = fmaxf(mx, __shfl_xor(mx, off));
    float e1 = __expf(v1-mx);
    float e2 = (tid<17) ? __expf(v2-mx) : 0.0f;
    float ssum = e1+e2;
    #pragma unroll
    for (int off=32; off; off>>=1) ssum += __shfl_xor(ssum, off);
    float sc = pv / ssum;
    t[bn*81 + tid] = e1*sc;
    if (tid<17) t[bn*81 + 64+tid] = e2*sc;
  }
}

// ---------------- Kg: gather einsums (x_in + state props + new_p) --------
// grid 648 blocks x 256 thr; row = b*81+m.
__global__ __launch_bounds__(256) void k_gather(
    const float* __restrict__ t, const float* __restrict__ skip,
    const float* __restrict__ c0i, const float* __restrict__ h0i,
    const float* __restrict__ c1i, const float* __restrict__ h1i,
    float* __restrict__ xin, float* __restrict__ h0p,
    float* __restrict__ h1p, float* __restrict__ c0p,
    float* __restrict__ c1p, float* __restrict__ pnext){
  int row = blockIdx.x;           // b*81+m
  int b = row / 81, m = row - b*81;
  int tid = threadIdx.x;
  __shared__ float tcol[81];
  if (tid < 81) tcol[tid] = t[(b*81+tid)*81 + m];
  __syncthreads();
  int nlim = (m==80) ? 81 : m;    // t[n,m]==0 for n>=m (unless m==80)
  float ts = 0.f;
  for (int n=0;n<nlim;n++) ts += tcol[n];
  if (tid==0) pnext[row] = ts;
  int o = row*256 + tid;
  if (ts == 0.0f){
    xin[o]=0.f; h0p[o]=0.f; h1p[o]=0.f; c0p[o]=0.f; c1p[o]=0.f;
    return;
  }
  float xa=0.f, c0a=0.f, h0a=0.f, c1a=0.f, h1a=0.f;
  for (int n=0;n<nlim;n++){
    float tv = tcol[n];
    int st = (b*81+n)*256 + tid;
    xa  = fmaf(tv, skip[((b*81+n)*81 + m)*256 + tid], xa);
    c0a = fmaf(tv, c0i[st], c0a);
    h0a = fmaf(tv, h0i[st], h0a);
    c1a = fmaf(tv, c1i[st], c1a);
    h1a = fmaf(tv, h1i[st], h1a);
  }
  float inv = 1.0f/(ts + 1e-7f);
  xin[o]=xa*inv; h0p[o]=h0a*inv; h1p[o]=h1a*inv; c0p[o]=c0a*inv; c1p[o]=c1a*inv;
}

// ---------------- Kx: ex-LSTM step via MFMA ------------------------------
// grid 41 blocks x 1024 thr (16 waves). M-tile = 16 REAL rows, N=1024, K=512 x2.
// D store MUST use all 64 lanes (rows = (lane>>4)*4 + reg covers 0-15).
#define RSX 520
__global__ __launch_bounds__(1024) void k_exlstm(
    const float* __restrict__ xin, const float* __restrict__ h0pg,
    const float* __restrict__ h1pg, const float* __restrict__ c0pg,
    const float* __restrict__ c1pg,
    const uint4* __restrict__ WAm, const uint4* __restrict__ WBm,
    const float* __restrict__ exb,
    float* __restrict__ c0o, float* __restrict__ h0o,
    float* __restrict__ c1o, float* __restrict__ h1o){
  int row0 = blockIdx.x*16;
  int tid = threadIdx.x;
  int w = tid >> 6, lane = tid & 63;
  int l15 = lane & 15, l4 = lane >> 4;
  int rp = tid >> 8, j = tid & 255;
  __shared__ float part[16*1024];       // 64KB
  __shared__ u16 Ah[16*RSX], Al[16*RSX];
  // ---- stage layer0 A: cols 0-255 x_in, 256-511 h0p (hi/lo planes)
  {
    int r16 = w, c4 = lane;             // one row per wave
    int grow = row0 + r16;
    float4 vx = {0,0,0,0}, vh = {0,0,0,0};
    if (grow < ROWS){
      vx = ((const float4*)xin)[grow*64 + c4];
      vh = ((const float4*)h0pg)[grow*64 + c4];
    }
    ushort4 hi4, lo4;
    hi4.x=f2bf(vx.x); lo4.x=f2bf(vx.x-bf2f(hi4.x));
    hi4.y=f2bf(vx.y); lo4.y=f2bf(vx.y-bf2f(hi4.y));
    hi4.z=f2bf(vx.z); lo4.z=f2bf(vx.z-bf2f(hi4.z));
    hi4.w=f2bf(vx.w); lo4.w=f2bf(vx.w-bf2f(hi4.w));
    *(ushort4*)&Ah[r16*RSX + c4*4] = hi4;
    *(ushort4*)&Al[r16*RSX + c4*4] = lo4;
    hi4.x=f2bf(vh.x); lo4.x=f2bf(vh.x-bf2f(hi4.x));
    hi4.y=f2bf(vh.y); lo4.y=f2bf(vh.y-bf2f(hi4.y));
    hi4.z=f2bf(vh.z); lo4.z=f2bf(vh.z-bf2f(hi4.z));
    hi4.w=f2bf(vh.w); lo4.w=f2bf(vh.w-bf2f(hi4.w));
    *(ushort4*)&Ah[r16*RSX + 256 + c4*4] = hi4;
    *(ushort4*)&Al[r16*RSX + 256 + c4*4] = lo4;
  }
  __syncthreads();
  const int aoff = l15*RSX + l4*8;
  // ---- layer0 matvec (16 ksteps, 2 planes, 4 tiles/wave)
  f32x4 acc0={0,0,0,0}, acc1={0,0,0,0}, acc2={0,0,0,0}, acc3={0,0,0,0};
  #pragma unroll 4
  for (int ks=0; ks<16; ks++){
    bfv8 ah = *(const bfv8*)&Ah[aoff + ks*32];
    bfv8 al = *(const bfv8*)&Al[aoff + ks*32];
    uint4 b0 = WAm[((w*4+0)*16 + ks)*64 + lane];
    uint4 b1 = WAm[((w*4+1)*16 + ks)*64 + lane];
    uint4 b2 = WAm[((w*4+2)*16 + ks)*64 + lane];
    uint4 b3 = WAm[((w*4+3)*16 + ks)*64 + lane];
    bfv8 v0=__builtin_bit_cast(bfv8,b0), v1=__builtin_bit_cast(bfv8,b1);
    bfv8 v2=__builtin_bit_cast(bfv8,b2), v3=__builtin_bit_cast(bfv8,b3);
    acc0=__builtin_amdgcn_mfma_f32_16x16x32_bf16(ah,v0,acc0,0,0,0);
    acc0=__builtin_amdgcn_mfma_f32_16x16x32_bf16(al,v0,acc0,0,0,0);
    acc1=__builtin_amdgcn_mfma_f32_16x16x32_bf16(ah,v1,acc1,0,0,0);
    acc1=__builtin_amdgcn_mfma_f32_16x16x32_bf16(al,v1,acc1,0,0,0);
    acc2=__builtin_amdgcn_mfma_f32_16x16x32_bf16(ah,v2,acc2,0,0,0);
    acc2=__builtin_amdgcn_mfma_f32_16x16x32_bf16(al,v2,acc2,0,0,0);
    acc3=__builtin_amdgcn_mfma_f32_16x16x32_bf16(ah,v3,acc3,0,0,0);
    acc3=__builtin_amdgcn_mfma_f32_16x16x32_bf16(al,v3,acc3,0,0,0);
  }
  {
    int r0 = l4*4;                       // ALL 64 lanes: rows 0-15
    #pragma unroll
    for (int q=0;q<4;q++){
      part[(r0+q)*1024 + w*64 +  0 + l15] = acc0[q];
      part[(r0+q)*1024 + w*64 + 16 + l15] = acc1[q];
      part[(r0+q)*1024 + w*64 + 32 + l15] = acc2[q];
      part[(r0+q)*1024 + w*64 + 48 + l15] = acc3[q];
    }
  }
  __syncthreads();
  // ---- layer0 cell: rows 4q+rp; write h0n + h1p into A for layer1
  float eb0=exb[j], eb1=exb[256+j], eb2=exb[512+j], eb3=exb[768+j];
  float c0s[4], h0s[4];
  #pragma unroll
  for (int q=0;q<4;q++){
    int r = 4*q + rp;
    int grow = row0 + r;
    bool g = grow < ROWS;
    float a0 = eb0 + part[r*1024 + j];
    float a1 = eb1 + part[r*1024 + 256 + j];
    float a2 = eb2 + part[r*1024 + 512 + j];
    float a3 = eb3 + part[r*1024 + 768 + j];
    float cp = g ? c0pg[grow*256 + j] : 0.f;
    float ii=sigf(a0), ff=sigf(a1), gg=tanh_fast(a2), oo=sigf(a3);
    float cn = ff*cp + ii*gg;
    float hn = oo*tanh_fast(cn);
    c0s[q]=cn; h0s[q]=hn;
    u16 hi = f2bf(hn);
    Ah[r*RSX + j] = hi; Al[r*RSX + j] = f2bf(hn - bf2f(hi));
    float hp = g ? h1pg[grow*256 + j] : 0.f;
    hi = f2bf(hp);
    Ah[r*RSX + 256 + j] = hi; Al[r*RSX + 256 + j] = f2bf(hp - bf2f(hi));
  }
  __syncthreads();
  // ---- layer1 matvec
  acc0=(f32x4){0,0,0,0}; acc1=(f32x4){0,0,0,0}; acc2=(f32x4){0,0,0,0}; acc3=(f32x4){0,0,0,0};
  #pragma unroll 4
  for (int ks=0; ks<16; ks++){
    bfv8 ah = *(const bfv8*)&Ah[aoff + ks*32];
    bfv8 al = *(const bfv8*)&Al[aoff + ks*32];
    uint4 b0 = WBm[((w*4+0)*16 + ks)*64 + lane];
    uint4 b1 = WBm[((w*4+1)*16 + ks)*64 + lane];
    uint4 b2 = WBm[((w*4+2)*16 + ks)*64 + lane];
    uint4 b3 = WBm[((w*4+3)*16 + ks)*64 + lane];
    bfv8 v0=__builtin_bit_cast(bfv8,b0), v1=__builtin_bit_cast(bfv8,b1);
    bfv8 v2=__builtin_bit_cast(bfv8,b2), v3=__builtin_bit_cast(bfv8,b3);
    acc0=__builtin_amdgcn_mfma_f32_16x16x32_bf16(ah,v0,acc0,0,0,0);
    acc0=__builtin_amdgcn_mfma_f32_16x16x32_bf16(al,v0,acc0,0,0,0);
    acc1=__builtin_amdgcn_mfma_f32_16x16x32_bf16(ah,v1,acc1,0,0,0);
    acc1=__builtin_amdgcn_mfma_f32_16x16x32_bf16(al,v1,acc1,0,0,0);
    acc2=__builtin_amdgcn_mfma_f32_16x16x32_bf16(ah,v2,acc2,0,0,0);
    acc2=__builtin_amdgcn_mfma_f32_16x16x32_bf16(al,v2,acc2,0,0,0);
    acc3=__builtin_amdgcn_mfma_f32_16x16x32_bf16(ah,v3,acc3,0,0,0);
    acc3=__builtin_amdgcn_mfma_f32_16x16x32_bf16(al,v3,acc3,0,0,0);
  }
  {
    int r0 = l4*4;                       // ALL 64 lanes: rows 0-15
    #pragma unroll
    for (int q=0;q<4;q++){
      part[(r0+q)*1024 + w*64 +  0 + l15] = acc0[q];
      part[(r0+q)*1024 + w*64 + 16 + l15] = acc1[q];
      part[(r0+q)*1024 + w*64 + 32 + l15] = acc2[q];
      part[(r0+q)*1024 + w*64 + 48 + l15] = acc3[q];
    }
  }
  __syncthreads();
  // ---- layer1 cell + store
  float eb4=exb[1024+j], eb5=exb[1280+j], eb6=exb[1536+j], eb7=exb[1792+j];
  #pragma unroll
  for (int q=0;q<4;q++){
    int r = 4*q + rp;
    int grow = row0 + r;
    bool g = grow < ROWS;
    float a0 = eb4 + part[r*1024 + j];
    float a1 = eb5 + part[r*1024 + 256 + j];
    float a2 = eb6 + part[r*1024 + 512 + j];
    float a3 = eb7 + part[r*1024 + 768 + j];
    float cp = g ? c1pg[grow*256 + j] : 0.f;
    float ii=sigf(a0), ff=sigf(a1), gg=tanh_fast(a2), oo=sigf(a3);
    float cn = ff*cp + ii*gg;
    float hn = oo*tanh_fast(cn);
    if (g){
      int o = grow*256 + j;
      c0o[o]=c0s[q]; h0o[o]=h0s[q]; c1o[o]=cn; h1o[o]=hn;
    }
  }
}

// ---------------- K6: out = h_exit @ wo + bo -----------------------------
__global__ __launch_bounds__(256) void k_out(
    const float* __restrict__ h1f, const int* __restrict__ exitIdx,
    const float* __restrict__ wo, const float* __restrict__ bo, float* __restrict__ out){
  __shared__ float hv[8][256];
  int tid = threadIdx.x;
  for (int i = tid; i < 2048; i += 256){
    int b = i >> 8, k = i & 255;
    hv[b][k] = h1f[(b*81 + exitIdx[b])*256 + k];
  }
  __syncthreads();
  int v = blockIdx.x*256 + tid;
  if (v >= 30000) return;
  float acc[8];
  #pragma unroll
  for (int b=0;b<8;b++) acc[b] = bo[v];
  for (int k=0;k<256;k++){
    float w = wo[k*30000 + v];
    #pragma unroll
    for (int b=0;b<8;b++) acc[b] = fmaf(hv[b][k], w, acc[b]);
  }
  #pragma unroll
  for (int b=0;b<8;b++) out[b*30000+v] = acc[b];
}

// ---------------- launch --------------------------------------------------
extern "C" void kernel_launch(void* const* d_in, const int* in_sizes, int n_in,
                              void* d_out, int out_size, void* d_ws, size_t ws_size,
                              hipStream_t stream){
  (void)in_sizes; (void)n_in; (void)out_size;
  const float* ne    = (const float*)d_in[0];
  const int*   exitI = (const int*)d_in[10];
  const float* stWx  = (const float*)d_in[12];
  const float* stb   = (const float*)d_in[14];
  const float* skWx  = (const float*)d_in[15];
  const float* skWh  = (const float*)d_in[16];
  const float* skb   = (const float*)d_in[17];
  const float* lnS   = (const float*)d_in[18];
  const float* lnB   = (const float*)d_in[19];
  const float* exWx  = (const float*)d_in[20];
  const float* exWh  = (const float*)d_in[21];
  const float* exb   = (const float*)d_in[22];
  const float* wk    = (const float*)d_in[23];
  const float* bk    = (const float*)d_in[24];
  const float* wsm   = (const float*)d_in[25];
  const float* bs    = (const float*)d_in[26];
  const float* w1    = (const float*)d_in[27];
  const float* wo    = (const float*)d_in[29];
  const float* bo    = (const float*)d_in[30];
  float* out = (float*)d_out;

  char* w = (char*)d_ws;
  size_t off = 0;
  auto alloc = [&](size_t bytes)->char*{
    char* p = w + off; off += (bytes + 255) & ~size_t(255); return p;
  };
  float4* X0   = (float4*)alloc((size_t)640*256*16);
  u32* W0m     = (u32*)alloc((size_t)131072*4);          // MFMA frag, K=256
  u32* W1m     = (u32*)alloc((size_t)262144*4);          // MFMA frag, K=512
  u32* WAm     = (u32*)alloc((size_t)262144*4);          // ex layer0, K=512
  u32* WBm     = (u32*)alloc((size_t)262144*4);          // ex layer1, K=512
  u32* wkp     = (u32*)alloc((size_t)512*256*4);
  u32* wspk    = (u32*)alloc((size_t)128*256*4);
  float* skip  = (float*)alloc((size_t)8*81*81*256*4);   // fp32
  u16* keys    = (u16*)alloc((size_t)8*81*81*256*2);     // bf16
  float* tb    = (float*)alloc((size_t)ROWS*81*4);
  float* p0    = (float*)alloc(ROWS*4);
  float* p1    = (float*)alloc(ROWS*4);
  float* stA   = (float*)alloc((size_t)4*ROWS*256*4);
  float* stB   = (float*)alloc((size_t)4*ROWS*256*4);
  float* xinb  = (float*)alloc((size_t)ROWS*256*4);
  float* h0pb  = (float*)alloc((size_t)ROWS*256*4);
  float* h1pb  = (float*)alloc((size_t)ROWS*256*4);
  float* c0pb  = (float*)alloc((size_t)ROWS*256*4);
  float* c1pb  = (float*)alloc((size_t)ROWS*256*4);
  if (off > ws_size) return;   // workspace too small — surfaces as absmax fail

  const size_t ST = (size_t)ROWS*256;
  float *A_c0=stA, *A_h0=stA+ST, *A_c1=stA+2*ST, *A_h1=stA+3*ST;
  float *B_c0=stB, *B_h0=stB+ST, *B_c1=stB+2*ST, *B_h1=stB+3*ST;

  hipMemsetAsync(skip, 0, (size_t)8*81*81*256*4, stream);
  hipMemsetAsync(stA, 0, (size_t)4*ROWS*256*4, stream);
  hipMemsetAsync(stB, 0, (size_t)4*ROWS*256*4, stream);
  k_init_p<<<3,256,0,stream>>>(p0);

  pack_mfma<<<512, 256, 0, stream>>>(skWh, skWh, W0m, 256);                        // Wh0
  pack_mfma<<<1024,256, 0, stream>>>(skWx+256*1024, skWh+256*1024, W1m, 512);      // [Wx1;Wh1]
  pack_mfma<<<1024,256, 0, stream>>>(exWx, exWh, WAm, 512);                        // [exWx0;exWh0]
  pack_mfma<<<1024,256, 0, stream>>>(exWx+256*1024, exWh+256*1024, WBm, 512);      // [exWx1;exWh1]
  pack_pairs<<<512, 256, 0, stream>>>(wk, wkp, 512, 256);
  pack_pairs<<<128, 256, 0, stream>>>(wsm, wspk, 128, 256);

  k_stmt_x0<<<320, 512, 0, stream>>>(ne, stWx, stb, skWx, skb, X0);
  k_skip_chains<<<80, 1024, 0, stream>>>(X0, (const uint4*)W0m, (const uint4*)W1m,
                                         skb, lnS, lnB, skip);
  k_keys<<<648, 256, 0, stream>>>(skip, wspk, bs, keys);

  float* pc = p0; float* pn = p1;
  for (int s=0; s<8; s++){
    float *ic0,*ih0,*ic1,*ih1,*oc0,*oh0,*oc1,*oh1;
    if ((s & 1) == 0){ ic0=A_c0; ih0=A_h0; ic1=A_c1; ih1=A_h1; oc0=B_c0; oh0=B_h0; oc1=B_c1; oh1=B_h1; }
    else             { ic0=B_c0; ih0=B_h0; ic1=B_c1; ih1=B_h1; oc0=A_c0; oh0=A_h0; oc1=A_c1; oh1=A_h1; }
    int mode = (s==0) ? 0 : ((s==7) ? 2 : 1);
    k_attn<<<648, 256, 0, stream>>>(ic0, ih0, ic1, ih1, wkp, bk, keys, w1, pc, tb, mode);
    k_gather<<<648, 256, 0, stream>>>(tb, skip, ic0, ih0, ic1, ih1,
                                      xinb, h0pb, h1pb, c0pb, c1pb, pn);
    k_exlstm<<<41, 1024, 0, stream>>>(xinb, h0pb, h1pb, c0pb, c1pb,
                                      (const uint4*)WAm, (const uint4*)WBm, exb,
                                      oc0, oh0, oc1, oh1);
    float* tmp = pc; pc = pn; pn = tmp;
  }
  // final states are in buffer A (step 7 writes A)
  k_out<<<(30000+255)/256, 256, 0, stream>>>(A_h1, exitI, wo, bo, out);
}

// Round 5
// 2019.488 us; speedup vs baseline: 2.0244x; 1.1227x over previous
//
#include <hip/hip_runtime.h>

typedef unsigned int  u32;
typedef unsigned short u16;
typedef float v2f __attribute__((ext_vector_type(2)));
typedef __attribute__((ext_vector_type(8))) short bfv8;   // 8 bf16 = 4 VGPR
typedef __attribute__((ext_vector_type(4))) float f32x4;

// B=8, NS=80, NN=81, H=256, L=2, STEPS=8, VOCAB=30000
#define ROWS 648          // B*NN
#define KROWS 52488       // 8*81*81 skip rows

__device__ __forceinline__ float sigf(float x){ return 1.0f/(1.0f+__expf(-x)); }
__device__ __forceinline__ float tanh_fast(float x){
  float e = __expf(-2.0f*fabsf(x));
  float r = (1.0f-e)/(1.0f+e);
  return copysignf(r,x);
}
__device__ __forceinline__ u16 f2bf(float f){        // RTNE f32->bf16
  u32 u = __float_as_uint(f);
  u += 0x7FFFu + ((u>>16)&1u);
  return (u16)(u>>16);
}
__device__ __forceinline__ u32 packbf2(float lo, float hi){
  return (u32)f2bf(lo) | ((u32)f2bf(hi)<<16);
}
__device__ __forceinline__ float bf2f(u16 v){ return __uint_as_float(((u32)v)<<16); }

// ---------------- weight packing ----------------------------------------
// MFMA B-fragment pack, concat two [256 x 1024] sources along K (N=1024).
// frag (tile t, kstep ks): lane l holds B[k = ks*32+(l>>4)*8+e][col = t*16+(l&15)]
__global__ void pack_mfma(const float* __restrict__ A, const float* __restrict__ Bm,
                          u32* __restrict__ dst, int K){
  int id = blockIdx.x*256 + threadIdx.x;
  int KS = K >> 5;
  int tot = 64*KS*64*4;
  if (id >= tot) return;
  int e2 = id & 3;
  int l  = (id >> 2) & 63;
  int rest = id >> 8;
  int ks = rest % KS;
  int t  = rest / KS;
  int k  = ks*32 + (l>>4)*8 + e2*2;
  int col = t*16 + (l&15);
  float v0 = (k   < 256) ? A[k*1024 + col]       : Bm[(k-256)*1024 + col];
  float v1 = (k+1 < 256) ? A[(k+1)*1024 + col]   : Bm[(k+1-256)*1024 + col];
  dst[id] = packbf2(v0, v1);
}

// Generic MFMA B-frag pack from one [K x (NT*16)] row-major matrix.
__global__ void pack_w(const float* __restrict__ src, u32* __restrict__ dst,
                       int K, int NT){
  int id = blockIdx.x*256 + threadIdx.x;
  int KS = K >> 5;
  int tot = NT*KS*64*4;
  if (id >= tot) return;
  int e2 = id & 3;
  int l  = (id >> 2) & 63;
  int rest = id >> 8;
  int ks = rest % KS;
  int t  = rest / KS;
  int k  = ks*32 + (l>>4)*8 + e2*2;
  int col = t*16 + (l&15);
  int ld = NT*16;
  dst[id] = packbf2(src[k*ld + col], src[(k+1)*ld + col]);
}

__global__ void k_init_p(float* __restrict__ p0){
  int i = blockIdx.x*256 + threadIdx.x;
  if (i < ROWS) p0[i] = ((i % 81)==0) ? 1.0f : 0.0f;
}

// ---------------- K1: statement embedder + X0 precompute ----------------
__global__ __launch_bounds__(512) void k_stmt_x0(
    const float* __restrict__ ne, const float* __restrict__ stWx, const float* __restrict__ stb,
    const float* __restrict__ skWx, const float* __restrict__ skb, float4* __restrict__ X0){
  __shared__ float xv[2][256];
  __shared__ float hv[2][256];
  int r = threadIdx.x >> 8, j = threadIdx.x & 255;
  int bn = blockIdx.x*2 + r;                    // 0..639
  xv[r][j] = ne[bn*256 + j];
  __syncthreads();
  float a0=stb[j], a2=stb[512+j], a3=stb[768+j];
  for (int k=0;k<256;k++){
    float x = xv[r][k];
    const float* w = stWx + k*1024;
    a0 = fmaf(x, w[j], a0); a2 = fmaf(x, w[512+j], a2); a3 = fmaf(x, w[768+j], a3);
  }
  float c = sigf(a0)*tanh_fast(a2);
  float h = sigf(a3)*tanh_fast(c);
  hv[r][j] = h;
  __syncthreads();
  a0=stb[1024+j]; a2=stb[1536+j]; a3=stb[1792+j];
  const float* W1 = stWx + 256*1024;
  for (int k=0;k<256;k++){
    float x = hv[r][k];
    const float* w = W1 + k*1024;
    a0 = fmaf(x, w[j], a0); a2 = fmaf(x, w[512+j], a2); a3 = fmaf(x, w[768+j], a3);
  }
  c = sigf(a0)*tanh_fast(a2);
  h = sigf(a3)*tanh_fast(c);
  __syncthreads();
  xv[r][j] = h;           // stmt row
  __syncthreads();
  float b0=skb[j], b1g=skb[256+j], b2=skb[512+j], b3=skb[768+j];
  for (int k=0;k<256;k++){
    float x = xv[r][k];
    const float* w = skWx + k*1024;
    b0 = fmaf(x, w[j], b0);     b1g = fmaf(x, w[256+j], b1g);
    b2 = fmaf(x, w[512+j], b2); b3 = fmaf(x, w[768+j], b3);
  }
  X0[bn*256 + j] = make_float4(b0,b1g,b2,b3);
}

// ---------------- K3: skip-encoder chains (MFMA) -------------------------
// M-tile = 16 rows, rows 8-15 ZERO PADDING; D-store via lanes<32 (rows 0-7).
#define RS0 264   // A-buf row stride (u16), layer0 K=256 (+8 pad)
#define RS1 520   // layer1 K=512 (+8 pad)
#define PS  1028  // part row stride (f32): (r*1028)%32 spreads l4 groups 2-way
__global__ __launch_bounds__(1024) void k_skip_chains(
    const float4* __restrict__ X0,
    const uint4* __restrict__ W0m, const uint4* __restrict__ W1m,
    const float* __restrict__ skb, const float* __restrict__ lnS, const float* __restrict__ lnB,
    float* __restrict__ skip){
  int s  = blockIdx.x;
  int tid = threadIdx.x;
  int w = tid >> 6, lane = tid & 63;
  int l15 = lane & 15, l4 = lane >> 4;
  int rp = tid >> 8, j = tid & 255;     // cell role: rows rp and rp+4
  __shared__ float part[8*PS];          // 32.9KB  D[row][col]
  __shared__ u16 A0h[16*RS0], A0l[16*RS0];  // layer0 A: h0_ln hi/lo
  __shared__ u16 A1h[16*RS1], A1l[16*RS1];  // layer1 A: [h0_raw | h1_ln] hi/lo
  __shared__ float red[4][16];
  for (int i=tid; i<16*RS0; i+=1024){ A0h[i]=0; A0l[i]=0; }
  for (int i=tid; i<16*RS1; i+=1024){ A1h[i]=0; A1l[i]=0; }
  float c0a=0.f, c1a=0.f, c0b=0.f, c1b=0.f;   // states rows rp / rp+4
  float s1b0=skb[1024+j], s1b1=skb[1280+j], s1b2=skb[1536+j], s1b3=skb[1792+j];
  float lS0=lnS[j], lS1=lnS[256+j], lS2=lnS[512+j], lS3=lnS[768+j];
  float lB0=lnB[j], lB1=lnB[256+j], lB2=lnB[512+j], lB3=lnB[768+j];
  const int aoff0 = l15*RS0 + l4*8;
  const int aoff1 = l15*RS1 + l4*8;
  __syncthreads();
  for (int idx=s; idx<80; idx++){
    float4 gxa = X0[(rp*80+idx)*256 + j];       // x-part gates, row rp
    float4 gxb = X0[((rp+4)*80+idx)*256 + j];   // row rp+4
    // ---- layer0 matvec: A0(h0_ln) x W0, K=256 (8 ksteps)
    f32x4 acc0={0,0,0,0}, acc1={0,0,0,0}, acc2={0,0,0,0}, acc3={0,0,0,0};
    #pragma unroll 4
    for (int ks=0; ks<8; ks++){
      bfv8 ah = *(const bfv8*)&A0h[aoff0 + ks*32];
      bfv8 al = *(const bfv8*)&A0l[aoff0 + ks*32];
      uint4 b0 = W0m[((w*4+0)*8 + ks)*64 + lane];
      uint4 b1 = W0m[((w*4+1)*8 + ks)*64 + lane];
      uint4 b2 = W0m[((w*4+2)*8 + ks)*64 + lane];
      uint4 b3 = W0m[((w*4+3)*8 + ks)*64 + lane];
      bfv8 v0=__builtin_bit_cast(bfv8,b0), v1=__builtin_bit_cast(bfv8,b1);
      bfv8 v2=__builtin_bit_cast(bfv8,b2), v3=__builtin_bit_cast(bfv8,b3);
      acc0=__builtin_amdgcn_mfma_f32_16x16x32_bf16(ah,v0,acc0,0,0,0);
      acc0=__builtin_amdgcn_mfma_f32_16x16x32_bf16(al,v0,acc0,0,0,0);
      acc1=__builtin_amdgcn_mfma_f32_16x16x32_bf16(ah,v1,acc1,0,0,0);
      acc1=__builtin_amdgcn_mfma_f32_16x16x32_bf16(al,v1,acc1,0,0,0);
      acc2=__builtin_amdgcn_mfma_f32_16x16x32_bf16(ah,v2,acc2,0,0,0);
      acc2=__builtin_amdgcn_mfma_f32_16x16x32_bf16(al,v2,acc2,0,0,0);
      acc3=__builtin_amdgcn_mfma_f32_16x16x32_bf16(ah,v3,acc3,0,0,0);
      acc3=__builtin_amdgcn_mfma_f32_16x16x32_bf16(al,v3,acc3,0,0,0);
    }
    if (lane < 32){
      int r0 = l4*4;
      #pragma unroll
      for (int q=0;q<4;q++){
        part[(r0+q)*PS + w*64 +  0 + l15] = acc0[q];
        part[(r0+q)*PS + w*64 + 16 + l15] = acc1[q];
        part[(r0+q)*PS + w*64 + 32 + l15] = acc2[q];
        part[(r0+q)*PS + w*64 + 48 + l15] = acc3[q];
      }
    }
    __syncthreads();                       // B1
    // ---- layer0 cell, rows rp and rp+4
    float h0na, h0nb;
    {
      float a0=gxa.x+part[rp*PS+j],     a1=gxa.y+part[rp*PS+256+j];
      float a2=gxa.z+part[rp*PS+512+j], a3=gxa.w+part[rp*PS+768+j];
      float ii=sigf(a0), ff=sigf(a1), gg=tanh_fast(a2), oo=sigf(a3);
      c0a = ff*c0a + ii*gg;
      h0na = oo*tanh_fast(c0a);
      u16 hi = f2bf(h0na);
      A1h[rp*RS1 + j] = hi;
      A1l[rp*RS1 + j] = f2bf(h0na - bf2f(hi));
    }
    {
      int rb = rp+4;
      float a0=gxb.x+part[rb*PS+j],     a1=gxb.y+part[rb*PS+256+j];
      float a2=gxb.z+part[rb*PS+512+j], a3=gxb.w+part[rb*PS+768+j];
      float ii=sigf(a0), ff=sigf(a1), gg=tanh_fast(a2), oo=sigf(a3);
      c0b = ff*c0b + ii*gg;
      h0nb = oo*tanh_fast(c0b);
      u16 hi = f2bf(h0nb);
      A1h[rb*RS1 + j] = hi;
      A1l[rb*RS1 + j] = f2bf(h0nb - bf2f(hi));
    }
    __syncthreads();                       // B2
    // ---- layer1 matvec: A1([h0_raw|h1_ln]) x W1, K=512 (16 ksteps)
    acc0=(f32x4){0,0,0,0}; acc1=(f32x4){0,0,0,0}; acc2=(f32x4){0,0,0,0}; acc3=(f32x4){0,0,0,0};
    #pragma unroll 4
    for (int ks=0; ks<16; ks++){
      bfv8 ah = *(const bfv8*)&A1h[aoff1 + ks*32];
      bfv8 al = *(const bfv8*)&A1l[aoff1 + ks*32];
      uint4 b0 = W1m[((w*4+0)*16 + ks)*64 + lane];
      uint4 b1 = W1m[((w*4+1)*16 + ks)*64 + lane];
      uint4 b2 = W1m[((w*4+2)*16 + ks)*64 + lane];
      uint4 b3 = W1m[((w*4+3)*16 + ks)*64 + lane];
      bfv8 v0=__builtin_bit_cast(bfv8,b0), v1=__builtin_bit_cast(bfv8,b1);
      bfv8 v2=__builtin_bit_cast(bfv8,b2), v3=__builtin_bit_cast(bfv8,b3);
      acc0=__builtin_amdgcn_mfma_f32_16x16x32_bf16(ah,v0,acc0,0,0,0);
      acc0=__builtin_amdgcn_mfma_f32_16x16x32_bf16(al,v0,acc0,0,0,0);
      acc1=__builtin_amdgcn_mfma_f32_16x16x32_bf16(ah,v1,acc1,0,0,0);
      acc1=__builtin_amdgcn_mfma_f32_16x16x32_bf16(al,v1,acc1,0,0,0);
      acc2=__builtin_amdgcn_mfma_f32_16x16x32_bf16(ah,v2,acc2,0,0,0);
      acc2=__builtin_amdgcn_mfma_f32_16x16x32_bf16(al,v2,acc2,0,0,0);
      acc3=__builtin_amdgcn_mfma_f32_16x16x32_bf16(ah,v3,acc3,0,0,0);
      acc3=__builtin_amdgcn_mfma_f32_16x16x32_bf16(al,v3,acc3,0,0,0);
    }
    if (lane < 32){
      int r0 = l4*4;
      #pragma unroll
      for (int q=0;q<4;q++){
        part[(r0+q)*PS + w*64 +  0 + l15] = acc0[q];
        part[(r0+q)*PS + w*64 + 16 + l15] = acc1[q];
        part[(r0+q)*PS + w*64 + 32 + l15] = acc2[q];
        part[(r0+q)*PS + w*64 + 48 + l15] = acc3[q];
      }
    }
    __syncthreads();                       // B3
    // ---- layer1 cell + LN, rows rp and rp+4
    float h1na, h1nb;
    {
      float a0=s1b0+part[rp*PS+j],     a1=s1b1+part[rp*PS+256+j];
      float a2=s1b2+part[rp*PS+512+j], a3=s1b3+part[rp*PS+768+j];
      float ii=sigf(a0), ff=sigf(a1), gg=tanh_fast(a2), oo=sigf(a3);
      c1a = ff*c1a + ii*gg;
      h1na = oo*tanh_fast(c1a);
      skip[((rp*81 + s)*81 + (idx+1))*256 + j] = h1na;
    }
    {
      int rb = rp+4;
      float a0=s1b0+part[rb*PS+j],     a1=s1b1+part[rb*PS+256+j];
      float a2=s1b2+part[rb*PS+512+j], a3=s1b3+part[rb*PS+768+j];
      float ii=sigf(a0), ff=sigf(a1), gg=tanh_fast(a2), oo=sigf(a3);
      c1b = ff*c1b + ii*gg;
      h1nb = oo*tanh_fast(c1b);
      skip[((rb*81 + s)*81 + (idx+1))*256 + j] = h1nb;
    }
    // ---- LayerNorm over concat(c0,h0n,c1,h1n) per row (1024 elems)
    float sm0 = c0a + h0na + c1a + h1na;
    float sq0 = c0a*c0a + h0na*h0na + c1a*c1a + h1na*h1na;
    float sm1 = c0b + h0nb + c1b + h1nb;
    float sq1 = c0b*c0b + h0nb*h0nb + c1b*c1b + h1nb*h1nb;
    #pragma unroll
    for (int off=32; off; off>>=1){
      sm0 += __shfl_xor(sm0, off); sq0 += __shfl_xor(sq0, off);
      sm1 += __shfl_xor(sm1, off); sq1 += __shfl_xor(sq1, off);
    }
    int wq = j >> 6;
    if ((j & 63) == 0){
      red[rp][wq*4+0]=sm0; red[rp][wq*4+1]=sq0;
      red[rp][wq*4+2]=sm1; red[rp][wq*4+3]=sq1;
    }
    __syncthreads();                       // B4
    sm0 = red[rp][0]+red[rp][4]+red[rp][8]+red[rp][12];
    sq0 = red[rp][1]+red[rp][5]+red[rp][9]+red[rp][13];
    sm1 = red[rp][2]+red[rp][6]+red[rp][10]+red[rp][14];
    sq1 = red[rp][3]+red[rp][7]+red[rp][11]+red[rp][15];
    {
      float mu = sm0 * (1.0f/1024.0f);
      float var = sq0 * (1.0f/1024.0f) - mu*mu;
      float rstd = rsqrtf(var + 1e-6f);
      c0a = (c0a - mu)*rstd*lS0 + lB0;
      float h0ln = (h0na - mu)*rstd*lS1 + lB1;
      c1a = (c1a - mu)*rstd*lS2 + lB2;
      float h1ln = (h1na - mu)*rstd*lS3 + lB3;
      u16 hi = f2bf(h0ln);
      A0h[rp*RS0 + j] = hi; A0l[rp*RS0 + j] = f2bf(h0ln - bf2f(hi));
      hi = f2bf(h1ln);
      A1h[rp*RS1 + 256 + j] = hi; A1l[rp*RS1 + 256 + j] = f2bf(h1ln - bf2f(hi));
    }
    {
      int rb = rp+4;
      float mu = sm1 * (1.0f/1024.0f);
      float var = sq1 * (1.0f/1024.0f) - mu*mu;
      float rstd = rsqrtf(var + 1e-6f);
      c0b = (c0b - mu)*rstd*lS0 + lB0;
      float h0ln = (h0nb - mu)*rstd*lS1 + lB1;
      c1b = (c1b - mu)*rstd*lS2 + lB2;
      float h1ln = (h1nb - mu)*rstd*lS3 + lB3;
      u16 hi = f2bf(h0ln);
      A0h[rb*RS0 + j] = hi; A0l[rb*RS0 + j] = f2bf(h0ln - bf2f(hi));
      hi = f2bf(h1ln);
      A1h[rb*RS1 + 256 + j] = hi; A1l[rb*RS1 + 256 + j] = f2bf(h1ln - bf2f(hi));
    }
    __syncthreads();                       // B5
  }
}

// ---------------- K4: keys = skip @ ws + bs  (MFMA, bf16 out) ------------
// grid 3281 x 1024 thr (16 waves). M-tile 16 skip rows; N=256 (wave w: tile w).
__global__ __launch_bounds__(1024) void k_keys(const float* __restrict__ skip,
    const uint4* __restrict__ WSm, const float* __restrict__ bs, u16* __restrict__ keys){
  int rows0 = blockIdx.x*16;
  int tid = threadIdx.x;
  int w = tid >> 6, lane = tid & 63;
  int l15 = lane & 15, l4 = lane >> 4;
  __shared__ u16 Ah[16*RS0], Al[16*RS0];
  __shared__ u16 kbuf[16*256];
  { // stage row w (fp32 -> hi/lo bf16)
    int grow = rows0 + w;
    float4 v = {0,0,0,0};
    if (grow < KROWS) v = ((const float4*)skip)[grow*64 + lane];
    ushort4 hi4, lo4;
    hi4.x=f2bf(v.x); lo4.x=f2bf(v.x-bf2f(hi4.x));
    hi4.y=f2bf(v.y); lo4.y=f2bf(v.y-bf2f(hi4.y));
    hi4.z=f2bf(v.z); lo4.z=f2bf(v.z-bf2f(hi4.z));
    hi4.w=f2bf(v.w); lo4.w=f2bf(v.w-bf2f(hi4.w));
    *(ushort4*)&Ah[w*RS0 + lane*4] = hi4;
    *(ushort4*)&Al[w*RS0 + lane*4] = lo4;
  }
  __syncthreads();
  const int aoff = l15*RS0 + l4*8;
  f32x4 acc = {0,0,0,0};
  #pragma unroll
  for (int ks=0; ks<8; ks++){
    bfv8 ah = *(const bfv8*)&Ah[aoff + ks*32];
    bfv8 al = *(const bfv8*)&Al[aoff + ks*32];
    uint4 b = WSm[(w*8 + ks)*64 + lane];
    bfv8 v = __builtin_bit_cast(bfv8, b);
    acc = __builtin_amdgcn_mfma_f32_16x16x32_bf16(ah, v, acc, 0,0,0);
    acc = __builtin_amdgcn_mfma_f32_16x16x32_bf16(al, v, acc, 0,0,0);
  }
  float bsv = bs[w*16 + l15];
  #pragma unroll
  for (int q=0;q<4;q++)
    kbuf[(l4*4+q)*256 + w*16 + l15] = f2bf(acc[q] + bsv);
  __syncthreads();
  int nval = KROWS - rows0; if (nval > 16) nval = 16;
  int words = nval*128;                 // u32 words (256 u16 per row)
  u32* kout = (u32*)keys + (size_t)rows0*128;
  const u32* kin = (const u32*)kbuf;
  for (int i=tid; i<words; i+=1024) kout[i] = kin[i];
}

// ---------------- Kb: logits -> softmax -> t (q precomputed) -------------
// mode 0: t[n,1]=pv (softmax over single col). mode 2: t[n,80]=pv.
// mode 1: logits for m>n || m==80 using qv from qb (bk included).
__global__ __launch_bounds__(256) void k_attn(
    const float* __restrict__ qb, const u16* __restrict__ keys,
    const float* __restrict__ w1, const float* __restrict__ pcur,
    float* __restrict__ t, int mode){
  int bn = blockIdx.x; int n = bn % 81;
  int tid = threadIdx.x;
  float pv = pcur[bn];
  if (pv == 0.0f){
    if (tid < 81) t[bn*81 + tid] = 0.0f;
    return;
  }
  if (mode == 0){ if (tid < 81) t[bn*81 + tid] = (tid==1)  ? pv : 0.0f; return; }
  if (mode == 2){ if (tid < 81) t[bn*81 + tid] = (tid==80) ? pv : 0.0f; return; }
  __shared__ float qv[256];
  __shared__ float lg[81];
  qv[tid] = qb[bn*256 + tid];
  if (tid < 81) lg[tid] = -3e38f;
  __syncthreads();
  int lane = tid & 63, wv = tid >> 6;
  float w1v0 = w1[lane], w1v1 = w1[64+lane], w1v2 = w1[128+lane], w1v3 = w1[192+lane];
  for (int m = wv; m < 81; m += 4){
    if (!(m>n || m==80)) continue;
    const u16* kr = keys + (bn*81+m)*256;
    float acc;
    acc  = tanh_fast(qv[lane]     + bf2f(kr[lane]))     * w1v0;
    acc += tanh_fast(qv[64+lane]  + bf2f(kr[64+lane]))  * w1v1;
    acc += tanh_fast(qv[128+lane] + bf2f(kr[128+lane])) * w1v2;
    acc += tanh_fast(qv[192+lane] + bf2f(kr[192+lane])) * w1v3;
    #pragma unroll
    for (int off=32; off; off>>=1) acc += __shfl_xor(acc, off);
    if (lane==0) lg[m] = acc;      // b1 omitted: softmax-invariant
  }
  __syncthreads();
  if (tid < 64){
    float v1 = lg[tid];
    float v2 = (tid<17) ? lg[64+tid] : -3e38f;
    float mx = fmaxf(v1, v2);
    #pragma unroll
    for (int off=32; off; off>>=1) mx = fmaxf(mx, __shfl_xor(mx, off));
    float e1 = __expf(v1-mx);
    float e2 = (tid<17) ? __expf(v2-mx) : 0.0f;
    float ssum = e1+e2;
    #pragma unroll
    for (int off=32; off; off>>=1) ssum += __shfl_xor(ssum, off);
    float sc = pv / ssum;
    t[bn*81 + tid] = e1*sc;
    if (tid<17) t[bn*81 + 64+tid] = e2*sc;
  }
}

// ---------------- Kg: gather einsums (x_in + state props + new_p) --------
__global__ __launch_bounds__(256) void k_gather(
    const float* __restrict__ t, const float* __restrict__ skip,
    const float* __restrict__ c0i, const float* __restrict__ h0i,
    const float* __restrict__ c1i, const float* __restrict__ h1i,
    float* __restrict__ xin, float* __restrict__ h0p,
    float* __restrict__ h1p, float* __restrict__ c0p,
    float* __restrict__ c1p, float* __restrict__ pnext){
  int row = blockIdx.x;           // b*81+m
  int b = row / 81, m = row - b*81;
  int tid = threadIdx.x;
  __shared__ float tcol[81];
  if (tid < 81) tcol[tid] = t[(b*81+tid)*81 + m];
  __syncthreads();
  int nlim = (m==80) ? 81 : m;    // t[n,m]==0 for n>=m (unless m==80)
  float ts = 0.f;
  for (int n=0;n<nlim;n++) ts += tcol[n];
  if (tid==0) pnext[row] = ts;
  int o = row*256 + tid;
  if (ts == 0.0f){
    xin[o]=0.f; h0p[o]=0.f; h1p[o]=0.f; c0p[o]=0.f; c1p[o]=0.f;
    return;
  }
  float xa=0.f, c0a=0.f, h0a=0.f, c1a=0.f, h1a=0.f;
  for (int n=0;n<nlim;n++){
    float tv = tcol[n];
    int st = (b*81+n)*256 + tid;
    xa  = fmaf(tv, skip[((b*81+n)*81 + m)*256 + tid], xa);
    c0a = fmaf(tv, c0i[st], c0a);
    h0a = fmaf(tv, h0i[st], h0a);
    c1a = fmaf(tv, c1i[st], c1a);
    h1a = fmaf(tv, h1i[st], h1a);
  }
  float inv = 1.0f/(ts + 1e-7f);
  xin[o]=xa*inv; h0p[o]=h0a*inv; h1p[o]=h1a*inv; c0p[o]=c0a*inv; c1p[o]=c1a*inv;
}

// ---------------- Kx: ex-LSTM step + fused q via MFMA --------------------
// grid 41 x 1024 thr. M-tile 16 REAL rows (D-store uses all 64 lanes).
// After states: q = [c0|h0|c1|h1] @ wk + bk (K=1024, N=256, tile = wave).
#define RSX 1032
#define PSX 1028
__global__ __launch_bounds__(1024) void k_exlstm(
    const float* __restrict__ xin, const float* __restrict__ h0pg,
    const float* __restrict__ h1pg, const float* __restrict__ c0pg,
    const float* __restrict__ c1pg,
    const uint4* __restrict__ WAm, const uint4* __restrict__ WBm,
    const uint4* __restrict__ WKm,
    const float* __restrict__ exb, const float* __restrict__ bk,
    float* __restrict__ c0o, float* __restrict__ h0o,
    float* __restrict__ c1o, float* __restrict__ h1o,
    float* __restrict__ qb){
  int row0 = blockIdx.x*16;
  int tid = threadIdx.x;
  int w = tid >> 6, lane = tid & 63;
  int l15 = lane & 15, l4 = lane >> 4;
  int rp = tid >> 8, j = tid & 255;
  __shared__ float part[16*PSX];        // 65.8KB
  __shared__ u16 Ah[16*RSX], Al[16*RSX];// 33KB each
  // ---- stage layer0 A: cols 0-255 x_in, 256-511 h0p (hi/lo planes)
  {
    int grow = row0 + w;
    float4 vx = {0,0,0,0}, vh = {0,0,0,0};
    if (grow < ROWS){
      vx = ((const float4*)xin)[grow*64 + lane];
      vh = ((const float4*)h0pg)[grow*64 + lane];
    }
    ushort4 hi4, lo4;
    hi4.x=f2bf(vx.x); lo4.x=f2bf(vx.x-bf2f(hi4.x));
    hi4.y=f2bf(vx.y); lo4.y=f2bf(vx.y-bf2f(hi4.y));
    hi4.z=f2bf(vx.z); lo4.z=f2bf(vx.z-bf2f(hi4.z));
    hi4.w=f2bf(vx.w); lo4.w=f2bf(vx.w-bf2f(hi4.w));
    *(ushort4*)&Ah[w*RSX + lane*4] = hi4;
    *(ushort4*)&Al[w*RSX + lane*4] = lo4;
    hi4.x=f2bf(vh.x); lo4.x=f2bf(vh.x-bf2f(hi4.x));
    hi4.y=f2bf(vh.y); lo4.y=f2bf(vh.y-bf2f(hi4.y));
    hi4.z=f2bf(vh.z); lo4.z=f2bf(vh.z-bf2f(hi4.z));
    hi4.w=f2bf(vh.w); lo4.w=f2bf(vh.w-bf2f(hi4.w));
    *(ushort4*)&Ah[w*RSX + 256 + lane*4] = hi4;
    *(ushort4*)&Al[w*RSX + 256 + lane*4] = lo4;
  }
  __syncthreads();
  const int aoff = l15*RSX + l4*8;
  // ---- layer0 matvec (16 ksteps, 2 planes, 4 tiles/wave)
  f32x4 acc0={0,0,0,0}, acc1={0,0,0,0}, acc2={0,0,0,0}, acc3={0,0,0,0};
  #pragma unroll 4
  for (int ks=0; ks<16; ks++){
    bfv8 ah = *(const bfv8*)&Ah[aoff + ks*32];
    bfv8 al = *(const bfv8*)&Al[aoff + ks*32];
    uint4 b0 = WAm[((w*4+0)*16 + ks)*64 + lane];
    uint4 b1 = WAm[((w*4+1)*16 + ks)*64 + lane];
    uint4 b2 = WAm[((w*4+2)*16 + ks)*64 + lane];
    uint4 b3 = WAm[((w*4+3)*16 + ks)*64 + lane];
    bfv8 v0=__builtin_bit_cast(bfv8,b0), v1=__builtin_bit_cast(bfv8,b1);
    bfv8 v2=__builtin_bit_cast(bfv8,b2), v3=__builtin_bit_cast(bfv8,b3);
    acc0=__builtin_amdgcn_mfma_f32_16x16x32_bf16(ah,v0,acc0,0,0,0);
    acc0=__builtin_amdgcn_mfma_f32_16x16x32_bf16(al,v0,acc0,0,0,0);
    acc1=__builtin_amdgcn_mfma_f32_16x16x32_bf16(ah,v1,acc1,0,0,0);
    acc1=__builtin_amdgcn_mfma_f32_16x16x32_bf16(al,v1,acc1,0,0,0);
    acc2=__builtin_amdgcn_mfma_f32_16x16x32_bf16(ah,v2,acc2,0,0,0);
    acc2=__builtin_amdgcn_mfma_f32_16x16x32_bf16(al,v2,acc2,0,0,0);
    acc3=__builtin_amdgcn_mfma_f32_16x16x32_bf16(ah,v3,acc3,0,0,0);
    acc3=__builtin_amdgcn_mfma_f32_16x16x32_bf16(al,v3,acc3,0,0,0);
  }
  {
    int r0 = l4*4;                       // ALL 64 lanes: rows 0-15
    #pragma unroll
    for (int q=0;q<4;q++){
      part[(r0+q)*PSX + w*64 +  0 + l15] = acc0[q];
      part[(r0+q)*PSX + w*64 + 16 + l15] = acc1[q];
      part[(r0+q)*PSX + w*64 + 32 + l15] = acc2[q];
      part[(r0+q)*PSX + w*64 + 48 + l15] = acc3[q];
    }
  }
  __syncthreads();
  // ---- layer0 cell: rows 4q+rp; write h0n + h1p into A for layer1
  float eb0=exb[j], eb1=exb[256+j], eb2=exb[512+j], eb3=exb[768+j];
  float c0s[4], h0s[4];
  #pragma unroll
  for (int q=0;q<4;q++){
    int r = 4*q + rp;
    int grow = row0 + r;
    bool g = grow < ROWS;
    float a0 = eb0 + part[r*PSX + j];
    float a1 = eb1 + part[r*PSX + 256 + j];
    float a2 = eb2 + part[r*PSX + 512 + j];
    float a3 = eb3 + part[r*PSX + 768 + j];
    float cp = g ? c0pg[grow*256 + j] : 0.f;
    float ii=sigf(a0), ff=sigf(a1), gg=tanh_fast(a2), oo=sigf(a3);
    float cn = ff*cp + ii*gg;
    float hn = oo*tanh_fast(cn);
    c0s[q]=cn; h0s[q]=hn;
    u16 hi = f2bf(hn);
    Ah[r*RSX + j] = hi; Al[r*RSX + j] = f2bf(hn - bf2f(hi));
    float hp = g ? h1pg[grow*256 + j] : 0.f;
    hi = f2bf(hp);
    Ah[r*RSX + 256 + j] = hi; Al[r*RSX + 256 + j] = f2bf(hp - bf2f(hi));
  }
  __syncthreads();
  // ---- layer1 matvec
  acc0=(f32x4){0,0,0,0}; acc1=(f32x4){0,0,0,0}; acc2=(f32x4){0,0,0,0}; acc3=(f32x4){0,0,0,0};
  #pragma unroll 4
  for (int ks=0; ks<16; ks++){
    bfv8 ah = *(const bfv8*)&Ah[aoff + ks*32];
    bfv8 al = *(const bfv8*)&Al[aoff + ks*32];
    uint4 b0 = WBm[((w*4+0)*16 + ks)*64 + lane];
    uint4 b1 = WBm[((w*4+1)*16 + ks)*64 + lane];
    uint4 b2 = WBm[((w*4+2)*16 + ks)*64 + lane];
    uint4 b3 = WBm[((w*4+3)*16 + ks)*64 + lane];
    bfv8 v0=__builtin_bit_cast(bfv8,b0), v1=__builtin_bit_cast(bfv8,b1);
    bfv8 v2=__builtin_bit_cast(bfv8,b2), v3=__builtin_bit_cast(bfv8,b3);
    acc0=__builtin_amdgcn_mfma_f32_16x16x32_bf16(ah,v0,acc0,0,0,0);
    acc0=__builtin_amdgcn_mfma_f32_16x16x32_bf16(al,v0,acc0,0,0,0);
    acc1=__builtin_amdgcn_mfma_f32_16x16x32_bf16(ah,v1,acc1,0,0,0);
    acc1=__builtin_amdgcn_mfma_f32_16x16x32_bf16(al,v1,acc1,0,0,0);
    acc2=__builtin_amdgcn_mfma_f32_16x16x32_bf16(ah,v2,acc2,0,0,0);
    acc2=__builtin_amdgcn_mfma_f32_16x16x32_bf16(al,v2,acc2,0,0,0);
    acc3=__builtin_amdgcn_mfma_f32_16x16x32_bf16(ah,v3,acc3,0,0,0);
    acc3=__builtin_amdgcn_mfma_f32_16x16x32_bf16(al,v3,acc3,0,0,0);
  }
  {
    int r0 = l4*4;                       // ALL 64 lanes: rows 0-15
    #pragma unroll
    for (int q=0;q<4;q++){
      part[(r0+q)*PSX + w*64 +  0 + l15] = acc0[q];
      part[(r0+q)*PSX + w*64 + 16 + l15] = acc1[q];
      part[(r0+q)*PSX + w*64 + 32 + l15] = acc2[q];
      part[(r0+q)*PSX + w*64 + 48 + l15] = acc3[q];
    }
  }
  __syncthreads();
  // ---- layer1 cell + store states; restage A as [c0|h0|c1|h1] for q
  float eb4=exb[1024+j], eb5=exb[1280+j], eb6=exb[1536+j], eb7=exb[1792+j];
  #pragma unroll
  for (int q=0;q<4;q++){
    int r = 4*q + rp;
    int grow = row0 + r;
    bool g = grow < ROWS;
    float a0 = eb4 + part[r*PSX + j];
    float a1 = eb5 + part[r*PSX + 256 + j];
    float a2 = eb6 + part[r*PSX + 512 + j];
    float a3 = eb7 + part[r*PSX + 768 + j];
    float cp = g ? c1pg[grow*256 + j] : 0.f;
    float ii=sigf(a0), ff=sigf(a1), gg=tanh_fast(a2), oo=sigf(a3);
    float cn = ff*cp + ii*gg;
    float hn = oo*tanh_fast(cn);
    if (g){
      int o = grow*256 + j;
      c0o[o]=c0s[q]; h0o[o]=h0s[q]; c1o[o]=cn; h1o[o]=hn;
    }
    u16 hi;
    hi = f2bf(c0s[q]); Ah[r*RSX +       j] = hi; Al[r*RSX +       j] = f2bf(c0s[q]-bf2f(hi));
    hi = f2bf(h0s[q]); Ah[r*RSX + 256 + j] = hi; Al[r*RSX + 256 + j] = f2bf(h0s[q]-bf2f(hi));
    hi = f2bf(cn);     Ah[r*RSX + 512 + j] = hi; Al[r*RSX + 512 + j] = f2bf(cn-bf2f(hi));
    hi = f2bf(hn);     Ah[r*RSX + 768 + j] = hi; Al[r*RSX + 768 + j] = f2bf(hn-bf2f(hi));
  }
  __syncthreads();
  // ---- q matvec: K=1024 (32 ksteps), N=256 (tile = wave)
  f32x4 accq = {0,0,0,0};
  #pragma unroll 4
  for (int ks=0; ks<32; ks++){
    bfv8 ah = *(const bfv8*)&Ah[aoff + ks*32];
    bfv8 al = *(const bfv8*)&Al[aoff + ks*32];
    uint4 b = WKm[(w*32 + ks)*64 + lane];
    bfv8 v = __builtin_bit_cast(bfv8, b);
    accq = __builtin_amdgcn_mfma_f32_16x16x32_bf16(ah, v, accq, 0,0,0);
    accq = __builtin_amdgcn_mfma_f32_16x16x32_bf16(al, v, accq, 0,0,0);
  }
  {
    int r0 = l4*4;
    #pragma unroll
    for (int q=0;q<4;q++)
      part[(r0+q)*260 + w*16 + l15] = accq[q];
  }
  __syncthreads();
  float bkv = bk[j];
  #pragma unroll
  for (int q=0;q<4;q++){
    int r = 4*q + rp;
    int grow = row0 + r;
    if (grow < ROWS) qb[grow*256 + j] = part[r*260 + j] + bkv;
  }
}

// ---------------- K6: out = h_exit @ wo + bo -----------------------------
__global__ __launch_bounds__(256) void k_out(
    const float* __restrict__ h1f, const int* __restrict__ exitIdx,
    const float* __restrict__ wo, const float* __restrict__ bo, float* __restrict__ out){
  __shared__ float hv[8][256];
  int tid = threadIdx.x;
  for (int i = tid; i < 2048; i += 256){
    int b = i >> 8, k = i & 255;
    hv[b][k] = h1f[(b*81 + exitIdx[b])*256 + k];
  }
  __syncthreads();
  int v = blockIdx.x*256 + tid;
  if (v >= 30000) return;
  float acc[8];
  #pragma unroll
  for (int b=0;b<8;b++) acc[b] = bo[v];
  for (int k=0;k<256;k++){
    float w = wo[k*30000 + v];
    #pragma unroll
    for (int b=0;b<8;b++) acc[b] = fmaf(hv[b][k], w, acc[b]);
  }
  #pragma unroll
  for (int b=0;b<8;b++) out[b*30000+v] = acc[b];
}

// ---------------- launch --------------------------------------------------
extern "C" void kernel_launch(void* const* d_in, const int* in_sizes, int n_in,
                              void* d_out, int out_size, void* d_ws, size_t ws_size,
                              hipStream_t stream){
  (void)in_sizes; (void)n_in; (void)out_size;
  const float* ne    = (const float*)d_in[0];
  const int*   exitI = (const int*)d_in[10];
  const float* stWx  = (const float*)d_in[12];
  const float* stb   = (const float*)d_in[14];
  const float* skWx  = (const float*)d_in[15];
  const float* skWh  = (const float*)d_in[16];
  const float* skb   = (const float*)d_in[17];
  const float* lnS   = (const float*)d_in[18];
  const float* lnB   = (const float*)d_in[19];
  const float* exWx  = (const float*)d_in[20];
  const float* exWh  = (const float*)d_in[21];
  const float* exb   = (const float*)d_in[22];
  const float* wk    = (const float*)d_in[23];
  const float* bk    = (const float*)d_in[24];
  const float* wsm   = (const float*)d_in[25];
  const float* bs    = (const float*)d_in[26];
  const float* w1    = (const float*)d_in[27];
  const float* wo    = (const float*)d_in[29];
  const float* bo    = (const float*)d_in[30];
  float* out = (float*)d_out;

  char* w = (char*)d_ws;
  size_t off = 0;
  auto alloc = [&](size_t bytes)->char*{
    char* p = w + off; off += (bytes + 255) & ~size_t(255); return p;
  };
  float4* X0   = (float4*)alloc((size_t)640*256*16);
  u32* W0m     = (u32*)alloc((size_t)131072*4);          // skip L0, K=256
  u32* W1m     = (u32*)alloc((size_t)262144*4);          // skip L1, K=512
  u32* WAm     = (u32*)alloc((size_t)262144*4);          // ex L0, K=512
  u32* WBm     = (u32*)alloc((size_t)262144*4);          // ex L1, K=512
  u32* WKm     = (u32*)alloc((size_t)131072*4);          // wk, K=1024 N=256
  u32* WSm     = (u32*)alloc((size_t)32768*4);           // ws, K=256 N=256
  float* skip  = (float*)alloc((size_t)8*81*81*256*4);   // fp32
  u16* keys    = (u16*)alloc((size_t)8*81*81*256*2);     // bf16
  float* tb    = (float*)alloc((size_t)ROWS*81*4);
  float* p0    = (float*)alloc(ROWS*4);
  float* p1    = (float*)alloc(ROWS*4);
  float* stA   = (float*)alloc((size_t)4*ROWS*256*4);
  float* stB   = (float*)alloc((size_t)4*ROWS*256*4);
  float* xinb  = (float*)alloc((size_t)ROWS*256*4);
  float* h0pb  = (float*)alloc((size_t)ROWS*256*4);
  float* h1pb  = (float*)alloc((size_t)ROWS*256*4);
  float* c0pb  = (float*)alloc((size_t)ROWS*256*4);
  float* c1pb  = (float*)alloc((size_t)ROWS*256*4);
  float* qb    = (float*)alloc((size_t)ROWS*256*4);
  if (off > ws_size) return;   // workspace too small — surfaces as absmax fail

  const size_t ST = (size_t)ROWS*256;
  float *A_c0=stA, *A_h0=stA+ST, *A_c1=stA+2*ST, *A_h1=stA+3*ST;
  float *B_c0=stB, *B_h0=stB+ST, *B_c1=stB+2*ST, *B_h1=stB+3*ST;

  hipMemsetAsync(skip, 0, (size_t)8*81*81*256*4, stream);
  hipMemsetAsync(stA, 0, (size_t)4*ROWS*256*4, stream);
  hipMemsetAsync(stB, 0, (size_t)4*ROWS*256*4, stream);
  k_init_p<<<3,256,0,stream>>>(p0);

  pack_mfma<<<512, 256, 0, stream>>>(skWh, skWh, W0m, 256);                        // Wh0
  pack_mfma<<<1024,256, 0, stream>>>(skWx+256*1024, skWh+256*1024, W1m, 512);      // [Wx1;Wh1]
  pack_mfma<<<1024,256, 0, stream>>>(exWx, exWh, WAm, 512);                        // [exWx0;exWh0]
  pack_mfma<<<1024,256, 0, stream>>>(exWx+256*1024, exWh+256*1024, WBm, 512);      // [exWx1;exWh1]
  pack_w<<<512, 256, 0, stream>>>(wk, WKm, 1024, 16);
  pack_w<<<128, 256, 0, stream>>>(wsm, WSm, 256, 16);

  k_stmt_x0<<<320, 512, 0, stream>>>(ne, stWx, stb, skWx, skb, X0);
  k_skip_chains<<<80, 1024, 0, stream>>>(X0, (const uint4*)W0m, (const uint4*)W1m,
                                         skb, lnS, lnB, skip);
  k_keys<<<(KROWS+15)/16, 1024, 0, stream>>>(skip, (const uint4*)WSm, bs, keys);

  float* pc = p0; float* pn = p1;
  for (int s=0; s<8; s++){
    float *ic0,*ih0,*ic1,*ih1,*oc0,*oh0,*oc1,*oh1;
    if ((s & 1) == 0){ ic0=A_c0; ih0=A_h0; ic1=A_c1; ih1=A_h1; oc0=B_c0; oh0=B_h0; oc1=B_c1; oh1=B_h1; }
    else             { ic0=B_c0; ih0=B_h0; ic1=B_c1; ih1=B_h1; oc0=A_c0; oh0=A_h0; oc1=A_c1; oh1=A_h1; }
    int mode = (s==0) ? 0 : ((s==7) ? 2 : 1);
    k_attn<<<648, 256, 0, stream>>>(qb, keys, w1, pc, tb, mode);
    k_gather<<<648, 256, 0, stream>>>(tb, skip, ic0, ih0, ic1, ih1,
                                      xinb, h0pb, h1pb, c0pb, c1pb, pn);
    k_exlstm<<<41, 1024, 0, stream>>>(xinb, h0pb, h1pb, c0pb, c1pb,
                                      (const uint4*)WAm, (const uint4*)WBm,
                                      (const uint4*)WKm, exb, bk,
                                      oc0, oh0, oc1, oh1, qb);
    float* tmp = pc; pc = pn; pn = tmp;
  }
  // final states are in buffer A (step 7 writes A)
  k_out<<<(30000+255)/256, 256, 0, stream>>>(A_h1, exitI, wo, bo, out);
}